// Round 14
// baseline (590.800 us; speedup 1.0000x reference)
//
#include <hip/hip_runtime.h>
#include <stdint.h>

// ---------------------------------------------------------------------------
// CPMAntAttention: B=2,S=1024,D=4096,H=32,DH=128
// Round 14: attn processes 2 q-tiles per block (shared staged K/V -> stage
// drain amortized over 2x compute, K/V HBM traffic halved; grid 512).
// Launch fusion: detect folded into canon_mask; vt+reduce_q merged.
// GEMMs identical to r13 (10-slot ring core, homogeneous rounds).
// ---------------------------------------------------------------------------

#define B_  2
#define S_  1024
#define D_  4096
#define H_  32
#define DH_ 128
#define M_  (B_ * S_)          // 2048
#define KSTR 8192              // row stride of fused KV output

typedef __attribute__((ext_vector_type(8))) short bf16x8;
typedef __attribute__((ext_vector_type(8))) unsigned short u16x8;
typedef __attribute__((ext_vector_type(4))) float f32x4;

static __device__ __forceinline__ unsigned short f32_to_bf16(float f) {
    unsigned int x = __float_as_uint(f);
    x += 0x7fffu + ((x >> 16) & 1u);   // RNE
    return (unsigned short)(x >> 16);
}

static __device__ __forceinline__ f32x4 mfma16(bf16x8 a, bf16x8 b, f32x4 c) {
    return __builtin_amdgcn_mfma_f32_16x16x32_bf16(a, b, c, 0, 0, 0);
}

#if defined(__has_builtin)
#if __has_builtin(__builtin_amdgcn_global_load_lds)
#define HAVE_GLOAD_LDS 1
#endif
#endif

#ifdef HAVE_GLOAD_LDS
#define GLD16(g, lbase, lane)                                                  \
    __builtin_amdgcn_global_load_lds(                                          \
        (const __attribute__((address_space(1))) void*)(g),                    \
        (__attribute__((address_space(3))) void*)(lbase), 16, 0, 0)
#else
#define GLD16(g, lbase, lane)                                                  \
    do { *(bf16x8*)((unsigned short*)(lbase) + (size_t)(lane) * 8) =           \
             *(const bf16x8*)(g); } while (0)
#endif

// ---------------------------------------------------------------------------
// canon_mask with inline dtype detection (first wave re-derives flag from the
// 1024-byte prefix; L2-broadcast, ~free). 0=u8/bool, 1=int32, 2=float32.
__global__ void canon_mask_kernel(const void* __restrict__ m,
                                  unsigned char* __restrict__ out, int n) {
    __shared__ int sflag;
    int t = threadIdx.x;
    if (t < 64) {
        uint4 v = ((const uint4*)m)[t];
        unsigned int ww[4] = {v.x, v.y, v.z, v.w};
        int nz_hi = 0, nz_lo01 = 0;
#pragma unroll
        for (int wi = 0; wi < 4; ++wi)
#pragma unroll
            for (int bi = 0; bi < 4; ++bi) {
                unsigned int byte = (ww[wi] >> (bi * 8)) & 0xffu;
                if (byte && bi != 0) nz_hi = 1;
                if (byte && bi <= 1) nz_lo01 = 1;
            }
        int any_hi = __any(nz_hi);
        int any_lo01 = __any(nz_lo01);
        if (t == 0) sflag = (!any_hi) ? 1 : ((!any_lo01) ? 2 : 0);
    }
    __syncthreads();
    int f = sflag;
    int i = blockIdx.x * 256 + t;
    if (i >= n) return;
    unsigned char v;
    if (f == 1)      v = (unsigned char)(((const int*)m)[i] != 0);
    else if (f == 2) v = (unsigned char)(((const float*)m)[i] != 0.0f);
    else             v = (unsigned char)(((const unsigned char*)m)[i] != 0);
    out[i] = v;
}

__global__ void cvt2_bf16_kernel(const float* __restrict__ a, const float* __restrict__ b,
                                 unsigned short* __restrict__ oa, unsigned short* __restrict__ ob) {
    int i = blockIdx.x * 256 + threadIdx.x;
    const int n4 = (B_ * S_ * D_) / 4;
    const float* src = (i < n4) ? a : b;
    unsigned short* dst = (i < n4) ? oa : ob;
    int j = (i < n4) ? i : i - n4;
    float4 v = ((const float4*)src)[j];
    ushort4 o;
    o.x = f32_to_bf16(v.x); o.y = f32_to_bf16(v.y);
    o.z = f32_to_bf16(v.z); o.w = f32_to_bf16(v.w);
    ((ushort4*)dst)[j] = o;
}

// W [4096][4096] fp32 -> WT [n][k] bf16; 64x64 tiles; 16B/lane writes.
__global__ __launch_bounds__(256) void transpose_all_kernel(
        const float* __restrict__ Wq, const float* __restrict__ Wk,
        const float* __restrict__ Wv, const float* __restrict__ Wo,
        unsigned short* __restrict__ WTq, unsigned short* __restrict__ WTkv,
        unsigned short* __restrict__ WTo) {
    __shared__ unsigned short lds[64][65];
    int which = blockIdx.x >> 12;
    int bid = blockIdx.x & 4095;
    const float* W = (which == 0) ? Wq : (which == 1) ? Wk : (which == 2) ? Wv : Wo;
    unsigned short* WT = (which == 0) ? WTq
                       : (which == 1) ? WTkv
                       : (which == 2) ? (WTkv + (size_t)4096 * 4096)
                                      : WTo;
    int bx = bid & 63;
    int by = bid >> 6;
    int t = threadIdx.x;
    int tr = t >> 4;
    int tc = (t & 15) * 4;
#pragma unroll
    for (int p = 0; p < 4; ++p) {
        int r = p * 16 + tr;
        float4 v = *(const float4*)(W + (size_t)(by * 64 + r) * D_ + bx * 64 + tc);
        lds[r][tc + 0] = f32_to_bf16(v.x);
        lds[r][tc + 1] = f32_to_bf16(v.y);
        lds[r][tc + 2] = f32_to_bf16(v.z);
        lds[r][tc + 3] = f32_to_bf16(v.w);
    }
    __syncthreads();
    int wn = t >> 3;
    int k0 = (t & 7) * 8;
#pragma unroll
    for (int p2 = 0; p2 < 2; ++p2) {
        int n = p2 * 32 + wn;
        u16x8 o;
#pragma unroll
        for (int j = 0; j < 8; ++j) o[j] = lds[k0 + j][n];
        *(u16x8*)(WT + (size_t)(bx * 64 + n) * D_ + by * 64 + k0) = o;
    }
}

// Fused: bid<2048 -> V-transpose; else reduce_q (independent, concurrent).
__global__ __launch_bounds__(256) void vtrq_kernel(const unsigned short* __restrict__ KV,
                                                   unsigned short* __restrict__ Vtw,
                                                   const float* __restrict__ P,
                                                   unsigned short* __restrict__ Qout) {
    __shared__ unsigned short lds[64][72];
    int bid = blockIdx.x;
    int t = threadIdx.x;
    if (bid < 2048) {
        int dt = bid & 1;
        int st = (bid >> 1) & 15;
        int h  = (bid >> 5) & 31;
        int b  = bid >> 10;
        int r = t >> 2;
        int c0 = (t & 3) * 16;
        const unsigned short* src =
            KV + (size_t)(b * S_ + st * 64 + r) * KSTR + 4096 + h * DH_ + dt * 64 + c0;
        bf16x8 v0 = *(const bf16x8*)(src);
        bf16x8 v1 = *(const bf16x8*)(src + 8);
        *(bf16x8*)&lds[r][c0] = v0;
        *(bf16x8*)&lds[r][c0 + 8] = v1;
        __syncthreads();
        unsigned short tmp[16];
#pragma unroll
        for (int i = 0; i < 16; ++i) tmp[i] = lds[c0 + i][r];
        unsigned short* dst =
            Vtw + ((size_t)((b * H_ + h) * DH_ + dt * 64 + r)) * S_ + st * 64 + c0;
        *(bf16x8*)dst = *(bf16x8*)&tmp[0];
        *(bf16x8*)(dst + 8) = *(bf16x8*)&tmp[8];
    } else {
        int i = (bid - 2048) * 256 + t;
        float4 a = ((const float4*)P)[i];
        float4 b = ((const float4*)(P + (size_t)M_ * D_))[i];
        ushort4 o;
        o.x = f32_to_bf16(a.x + b.x); o.y = f32_to_bf16(a.y + b.y);
        o.z = f32_to_bf16(a.z + b.z); o.w = f32_to_bf16(a.w + b.w);
        ((ushort4*)Qout)[i] = o;
    }
}

// ---------------------------------------------------------------------------
// Phase-pipelined GEMM core (r13): 10-slot ring (160 KiB), prefetch dist 6,
// vmcnt(4) steady / vmcnt(0) final tile. Tile 256x256, BK=64, 512 thr.
__device__ __forceinline__ void gemm_core(const unsigned short* __restrict__ A,
                                          const unsigned short* __restrict__ BT,
                                          void* __restrict__ C, int out_f32,
                                          int m0, int n0, int cstride,
                                          int koff, int NT, char* ldsc) {
    const int t = threadIdx.x;
    const int w = t >> 6, l = t & 63;
    const int lr = l & 15, lg = l >> 4;
    const int wmh = w >> 2;
    const int walf = w & 3;
    const int wm = wmh << 7;
    const int wn = walf << 6;

    const int ca0 = lg ^ (lr & 7);
    const int aoff0 = lr * 128 + (ca0 << 4);
    const int aoff1 = lr * 128 + ((ca0 ^ 4) << 4);
    const int boff0 = ((walf & 1) * 64 + lr) * 128 + (ca0 << 4);
    const int boff1 = ((walf & 1) * 64 + lr) * 128 + ((ca0 ^ 4) << 4);

    const int srow = t >> 3;
    const int sch = (t & 7) ^ (srow & 7);
    const size_t soff0 = (size_t)srow * 4096 + (size_t)(sch << 3);
    const size_t soff1 = soff0 + (size_t)64 * 4096;
    const int ldso = w << 10;

    f32x4 ac[8][4];
    f32x4 vzero = {0.f, 0.f, 0.f, 0.f};
#pragma unroll
    for (int i = 0; i < 8; ++i)
#pragma unroll
        for (int j = 0; j < 4; ++j) ac[i][j] = vzero;

#define STAGE_ELEM(E, SS)                                                      \
    do {                                                                       \
        int er_ = (E) & 3;                                                     \
        const unsigned short* mb_ = (er_ < 2)                                  \
            ? A + (size_t)(m0 + ((er_ & 1) << 7)) * 4096                       \
            : BT + (size_t)(n0 + ((er_ & 1) << 7)) * 4096;                     \
        mb_ += (size_t)((((E) >> 2) << 6) + koff);                             \
        char* d0_ = ldsc + (SS) * 16384 + ldso;                                \
        GLD16(mb_ + soff0, d0_, l);                                            \
        GLD16(mb_ + soff1, d0_ + 8192, l);                                     \
    } while (0)

#pragma unroll
    for (int e = 0; e < 6; ++e) STAGE_ELEM(e, e);

    const int NT4 = NT << 2;
    int E = 6, ss = 6, s0 = 0;
    bf16x8 bfr[4][2];

#pragma unroll 1
    for (int tau = 0; tau < NT; ++tau) {
        int sA = s0 + wmh;             if (sA >= 10) sA -= 10;
        int sB = s0 + 2 + (walf >> 1); if (sB >= 10) sB -= 10;
        const char* pA0 = ldsc + sA * 16384 + aoff0;
        const char* pA1 = ldsc + sA * 16384 + aoff1;
        const char* pB0 = ldsc + sB * 16384 + boff0;
        const char* pB1 = ldsc + sB * 16384 + boff1;
#pragma unroll
        for (int r = 0; r < 4; ++r) {
            if (r == 0) {
                if (tau == NT - 1)
                    asm volatile("s_waitcnt vmcnt(0)" ::: "memory");
                else
                    asm volatile("s_waitcnt vmcnt(4)" ::: "memory");
            }
            __builtin_amdgcn_s_barrier();
            asm volatile("" ::: "memory");
            if (r == 0) {
#pragma unroll
                for (int nf = 0; nf < 4; ++nf) {
                    bfr[nf][0] = *(const bf16x8*)(pB0 + nf * 2048);
                    bfr[nf][1] = *(const bf16x8*)(pB1 + nf * 2048);
                }
            }
            bf16x8 af[2][2];
            int mfb = r << 1;
#pragma unroll
            for (int j = 0; j < 2; ++j) {
                af[j][0] = *(const bf16x8*)(pA0 + (mfb + j) * 2048);
                af[j][1] = *(const bf16x8*)(pA1 + (mfb + j) * 2048);
            }
            if (E < NT4) STAGE_ELEM(E, ss);
            ++E; ss = (ss == 9) ? 0 : ss + 1;
            __builtin_amdgcn_s_setprio(1);
#pragma unroll
            for (int j = 0; j < 2; ++j)
#pragma unroll
                for (int nf = 0; nf < 4; ++nf) {
                    ac[mfb + j][nf] = mfma16(af[j][0], bfr[nf][0], ac[mfb + j][nf]);
                    ac[mfb + j][nf] = mfma16(af[j][1], bfr[nf][1], ac[mfb + j][nf]);
                }
            __builtin_amdgcn_s_setprio(0);
        }
        s0 += 4; if (s0 >= 10) s0 -= 10;
    }
#undef STAGE_ELEM

#pragma unroll
    for (int mf = 0; mf < 8; ++mf)
#pragma unroll
        for (int nf = 0; nf < 4; ++nf)
#pragma unroll
            for (int q = 0; q < 4; ++q) {
                int row = m0 + wm + mf * 16 + lg * 4 + q;
                int col = n0 + wn + nf * 16 + lr;
                if (out_f32)
                    ((float*)C)[(size_t)row * cstride + col] = ac[mf][nf][q];
                else
                    ((unsigned short*)C)[(size_t)row * cstride + col] = f32_to_bf16(ac[mf][nf][q]);
            }
}

// 512 blocks, two homogeneous rounds: 0..255 KV full-K, 256..511 Q splitK2.
__global__ __launch_bounds__(512, 1) void gemm_qkv_kernel(
        const unsigned short* __restrict__ Aq, const unsigned short* __restrict__ Bq,
        float* __restrict__ Pq,
        const unsigned short* __restrict__ Akv, const unsigned short* __restrict__ Bkv,
        unsigned short* __restrict__ Ckv) {
    __shared__ char ldsbuf[10 * 16384];
    int bid = blockIdx.x;
    if (bid < 256) {
        int bm = bid & 7, bn = bid >> 3;
        gemm_core(Akv, Bkv, Ckv, 0, bm << 8, bn << 8, 8192, 0, 64, ldsbuf);
    } else {
        int e = bid - 256;
        int bm = e & 7;
        int rest = e >> 3;
        int bn = rest & 15;
        int ks = rest >> 4;
        gemm_core(Aq, Bq, Pq + (size_t)ks * M_ * D_, 1, bm << 8, bn << 8, 4096,
                  ks * 2048, 32, ldsbuf);
    }
}

__global__ __launch_bounds__(512, 1) void gemm_o_kernel(
        const unsigned short* __restrict__ A, const unsigned short* __restrict__ BT,
        float* __restrict__ P) {
    __shared__ char ldsbuf[10 * 16384];
    int bid = blockIdx.x;
    int bm = bid & 7;
    int rest = bid >> 3;
    int bn = rest & 15;
    int ks = rest >> 4;
    gemm_core(A, BT, P + (size_t)ks * M_ * D_, 1, bm << 8, bn << 8, 4096,
              ks * 2048, 32, ldsbuf);
}

__global__ void reduce_o_kernel(const float* __restrict__ P, float* __restrict__ out) {
    int i = blockIdx.x * 256 + threadIdx.x;
    float4 a = ((const float4*)P)[i];
    float4 b = ((const float4*)(P + (size_t)M_ * D_))[i];
    float4 o; o.x = a.x + b.x; o.y = a.y + b.y; o.z = a.z + b.z; o.w = a.w + b.w;
    ((float4*)out)[i] = o;
}

// ---------------------------------------------------------------------------
// Flash attention r14: 2 q-tiles per block (qt, qt+8) share staged K/V.
// dbuf global_load_lds, swapped QK^T, wide bias/mask, lane-local softmax,
// XCD grouping. Grid 512, 2 blocks/CU.
#define NEGF (-1e30f)
__global__ __launch_bounds__(256, 2) void attn_kernel(const unsigned short* __restrict__ Qw,
                                                      const unsigned short* __restrict__ KV,
                                                      const unsigned short* __restrict__ Vtw,
                                                      const float* __restrict__ bias,
                                                      const unsigned char* __restrict__ maskc,
                                                      unsigned short* __restrict__ ctx) {
    __shared__ unsigned short Kbuf[2][64 * 128];
    __shared__ unsigned short Vbuf[2][128 * 64];
    __shared__ unsigned short Plds[4][16 * 72];

    // 512 blocks: xcd = x&7; qt-pair = (x>>3)&7 -> tiles qt, qt+8; head group.
    int x = blockIdx.x;
    int xcd = x & 7;
    int rest = x >> 3;           // 0..63
    int qt = rest & 7;
    int gq = rest >> 3;          // 0..7
    int g = gq * 8 + xcd;        // 0..63
    int b = g >> 5, h = g & 31;

    int t = threadIdx.x, w = t >> 6, l = t & 63;
    int lr = l & 15, lg = l >> 4;
    int q0 = (qt << 6) + (w << 4);         // A-set rows; B-set = +512

    bf16x8 qfA[4], qfB[4];
    const unsigned short* Qp = Qw + ((size_t)(b * S_ + q0 + lr)) * D_ + h * DH_ + lg * 8;
#pragma unroll
    for (int kf = 0; kf < 4; ++kf) {
        qfA[kf] = *(const bf16x8*)(Qp + kf * 32);
        qfB[kf] = *(const bf16x8*)(Qp + (size_t)512 * D_ + kf * 32);
    }

    f32x4 oA[8], oB[8];
    f32x4 vzero = {0.f, 0.f, 0.f, 0.f};
#pragma unroll
    for (int i = 0; i < 8; ++i) { oA[i] = vzero; oB[i] = vzero; }
    float mA = NEGF, lA = 0.f, mB = NEGF, lB = 0.f;

    const float* biaspA = bias + (((size_t)(b * H_ + h)) << 20)
                               + (((size_t)(q0 + lr)) << 10);
    const float* biaspB = biaspA + ((size_t)512 << 10);
    const unsigned char* mpA = maskc + ((size_t)b << 20)
                               + (((size_t)(q0 + lr)) << 10);
    const unsigned char* mpB = mpA + ((size_t)512 << 10);
    const unsigned short* Kg = KV + (size_t)(b * S_) * KSTR + h * DH_;
    const unsigned short* Vg = Vtw + (((size_t)(b * H_ + h)) * DH_) * S_;

    float4 brA0[4], brA1[4], brB0[4], brB1[4];
    unsigned int mrA0[4], mrA1[4], mrB0[4], mrB1[4];

#define STAGE_KV(KT, BUF)                                                          \
    do { int kv0_ = (KT) << 6;                                                     \
        _Pragma("unroll")                                                          \
        for (int c = 0; c < 4; ++c) {                                              \
            int seg = (w << 2) + c;                                                \
            int krow = (seg << 2) + (l >> 4);                                      \
            int kch = (l & 15) ^ (krow & 7);                                       \
            GLD16(Kg + (size_t)(kv0_ + krow) * KSTR + (kch << 3),                  \
                  &Kbuf[BUF][seg << 9], l);                                        \
            int vrow = (seg << 3) + (l >> 3);                                      \
            int vch = (l & 7) ^ (vrow & 7);                                        \
            GLD16(Vg + (size_t)vrow * S_ + kv0_ + (vch << 3),                      \
                  &Vbuf[BUF][seg << 9], l);                                        \
        }                                                                          \
    } while (0)

#define LOAD_BM(BR, MR, BP, MP, KT)                                                \
    do { int kv0_ = (KT) << 6;                                                     \
        _Pragma("unroll")                                                          \
        for (int nb = 0; nb < 4; ++nb) {                                           \
            BR[nb] = *(const float4*)(BP + kv0_ + (nb << 4) + (lg << 2));          \
            MR[nb] = *(const unsigned int*)(MP + kv0_ + (nb << 4) + (lg << 2));    \
        }                                                                          \
    } while (0)

#define COMPUTE(BUF, BR, MR, QF, O, MRUN, LRUN)                                    \
    do {                                                                           \
        f32x4 s_[4];                                                               \
        __builtin_amdgcn_s_setprio(1);                                             \
        _Pragma("unroll")                                                          \
        for (int nb = 0; nb < 4; ++nb) {                                           \
            s_[nb] = vzero;                                                        \
            int krow = (nb << 4) + lr;                                             \
            _Pragma("unroll")                                                      \
            for (int kf = 0; kf < 4; ++kf) {                                       \
                int ba = ((krow << 8) + (((kf << 5) + (lg << 3)) << 1))            \
                         ^ ((krow & 7) << 4);                                      \
                bf16x8 kfr = *(const bf16x8*)((const char*)Kbuf[BUF] + ba);        \
                s_[nb] = mfma16(kfr, QF[kf], s_[nb]);                              \
            }                                                                      \
        }                                                                          \
        __builtin_amdgcn_s_setprio(0);                                             \
        float sv[4][4];                                                            \
        _Pragma("unroll")                                                          \
        for (int nb = 0; nb < 4; ++nb) {                                           \
            float bb[4] = {BR[nb].x, BR[nb].y, BR[nb].z, BR[nb].w};                \
            _Pragma("unroll")                                                      \
            for (int r = 0; r < 4; ++r) {                                          \
                float x2 = fmaf(s_[nb][r], 0.08838834764831845f, bb[r]);           \
                sv[nb][r] = ((MR[nb] >> (r * 8)) & 0xffu) ? x2 : NEGF;             \
            }                                                                      \
        }                                                                          \
        float mt = sv[0][0];                                                       \
        _Pragma("unroll")                                                          \
        for (int nb = 0; nb < 4; ++nb)                                             \
            _Pragma("unroll")                                                      \
            for (int r = 0; r < 4; ++r) mt = fmaxf(mt, sv[nb][r]);                 \
        mt = fmaxf(mt, __shfl_xor(mt, 16, 64));                                    \
        mt = fmaxf(mt, __shfl_xor(mt, 32, 64));                                    \
        float mn = fmaxf(MRUN, mt);                                                \
        float al = __expf(MRUN - mn);                                              \
        MRUN = mn;                                                                 \
        float rs = 0.f;                                                            \
        _Pragma("unroll")                                                          \
        for (int nb = 0; nb < 4; ++nb)                                             \
            _Pragma("unroll")                                                      \
            for (int r = 0; r < 4; ++r) {                                          \
                sv[nb][r] = __expf(sv[nb][r] - MRUN);                              \
                rs += sv[nb][r];                                                   \
            }                                                                      \
        rs += __shfl_xor(rs, 16, 64);                                              \
        rs += __shfl_xor(rs, 32, 64);                                              \
        LRUN = LRUN * al + rs;                                                     \
        float alm[4];                                                              \
        _Pragma("unroll")                                                          \
        for (int r = 0; r < 4; ++r) alm[r] = __shfl(al, (lg << 2) + r, 64);        \
        _Pragma("unroll")                                                          \
        for (int nb2 = 0; nb2 < 8; ++nb2) {                                        \
            O[nb2][0] *= alm[0]; O[nb2][1] *= alm[1];                              \
            O[nb2][2] *= alm[2]; O[nb2][3] *= alm[3];                              \
        }                                                                          \
        _Pragma("unroll")                                                          \
        for (int nb = 0; nb < 4; ++nb)                                             \
            _Pragma("unroll")                                                      \
            for (int r = 0; r < 4; ++r)                                            \
                Plds[w][lr * 72 + (nb << 4) + (lg << 2) + r] = f32_to_bf16(sv[nb][r]); \
        __builtin_amdgcn_s_setprio(1);                                             \
        _Pragma("unroll")                                                          \
        for (int kf2 = 0; kf2 < 2; ++kf2) {                                        \
            bf16x8 pf = *(const bf16x8*)&Plds[w][lr * 72 + (kf2 << 5) + (lg << 3)]; \
            _Pragma("unroll")                                                      \
            for (int nb2 = 0; nb2 < 8; ++nb2) {                                    \
                int dh = (nb2 << 4) + lr;                                          \
                int ba = ((dh << 7) + (((kf2 << 5) + (lg << 3)) << 1))             \
                         ^ ((dh & 7) << 4);                                        \
                bf16x8 vf = *(const bf16x8*)((const char*)Vbuf[BUF] + ba);         \
                O[nb2] = mfma16(pf, vf, O[nb2]);                                   \
            }                                                                      \
        }                                                                          \
        __builtin_amdgcn_s_setprio(0);                                             \
    } while (0)

    STAGE_KV(0, 0);
    LOAD_BM(brA0, mrA0, biaspA, mpA, 0);
    LOAD_BM(brB0, mrB0, biaspB, mpB, 0);

#pragma unroll 1
    for (int kt = 0; kt < 16; kt += 2) {
        __syncthreads();
        STAGE_KV(kt + 1, 1);
        LOAD_BM(brA1, mrA1, biaspA, mpA, kt + 1);
        LOAD_BM(brB1, mrB1, biaspB, mpB, kt + 1);
        COMPUTE(0, brA0, mrA0, qfA, oA, mA, lA);
        COMPUTE(0, brB0, mrB0, qfB, oB, mB, lB);
        __syncthreads();
        if (kt < 14) {
            STAGE_KV(kt + 2, 0);
            LOAD_BM(brA0, mrA0, biaspA, mpA, kt + 2);
            LOAD_BM(brB0, mrB0, biaspB, mpB, kt + 2);
        }
        COMPUTE(1, brA1, mrA1, qfA, oA, mA, lA);
        COMPUTE(1, brB1, mrB1, qfB, oB, mB, lB);
    }

    // epilogue: both q-sets
    float lmA[4], lmB[4];
#pragma unroll
    for (int r = 0; r < 4; ++r) {
        lmA[r] = __shfl(lA, (lg << 2) + r, 64);
        lmB[r] = __shfl(lB, (lg << 2) + r, 64);
    }
#pragma unroll
    for (int r = 0; r < 4; ++r) {
        float invA = lmA[r] > 0.f ? 1.0f / lmA[r] : 0.f;
        float invB = lmB[r] > 0.f ? 1.0f / lmB[r] : 0.f;
        int q = q0 + (lg << 2) + r;
        unsigned short* cpA = ctx + ((size_t)(b * S_ + q)) * D_ + h * DH_ + lr;
        unsigned short* cpB = cpA + (size_t)512 * D_;
#pragma unroll
        for (int nb2 = 0; nb2 < 8; ++nb2) {
            cpA[nb2 * 16] = f32_to_bf16(oA[nb2][r] * invA);
            cpB[nb2 * 16] = f32_to_bf16(oB[nb2][r] * invB);
        }
    }
#undef STAGE_KV
#undef LOAD_BM
#undef COMPUTE
}

// ---------------------------------------------------------------------------
extern "C" void kernel_launch(void* const* d_in, const int* in_sizes, int n_in,
                              void* d_out, int out_size, void* d_ws, size_t ws_size,
                              hipStream_t stream) {
    const float* hq   = (const float*)d_in[0];
    const float* hkv  = (const float*)d_in[1];
    const void*  mask = d_in[2];
    const float* bias = (const float*)d_in[3];
    const float* Wq   = (const float*)d_in[4];
    const float* Wk   = (const float*)d_in[5];
    const float* Wv   = (const float*)d_in[6];
    const float* Wo   = (const float*)d_in[7];
    float* out = (float*)d_out;

    char* ws = (char*)d_ws;
    unsigned char* mask_c = (unsigned char*)ws;                        // 2 MB
    unsigned short* hq_b  = (unsigned short*)(ws + (2u << 20) + 4096); // 16 MB
    unsigned short* hkv_b = hq_b + ((size_t)1 << 23);                  // 16 MB
    unsigned short* WTq   = hkv_b + ((size_t)1 << 23);                 // 32 MB
    unsigned short* WTo   = WTq + ((size_t)1 << 24);                   // 32 MB
    unsigned short* WTkv  = WTo + ((size_t)1 << 24);                   // 64 MB
    unsigned short* Qws   = WTkv + ((size_t)1 << 25);                  // 16 MB
    unsigned short* KVws  = Qws + ((size_t)1 << 23);                   // 32 MB
    unsigned short* Cws   = KVws + ((size_t)1 << 24);                  // 16 MB
    unsigned short* Vtw   = Cws + ((size_t)1 << 23);                   // 16 MB
    float* Pws            = (float*)(Vtw + ((size_t)1 << 23));         // 64 MB

    canon_mask_kernel<<<8192, 256, 0, stream>>>(mask, mask_c, B_ * S_ * S_);
    cvt2_bf16_kernel<<<16384, 256, 0, stream>>>(hq, hkv, hq_b, hkv_b);
    transpose_all_kernel<<<16384, 256, 0, stream>>>(Wq, Wk, Wv, Wo, WTq, WTkv, WTo);

    gemm_qkv_kernel<<<512, 512, 0, stream>>>(hq_b, WTq, Pws, hkv_b, WTkv, KVws);
    vtrq_kernel<<<10240, 256, 0, stream>>>(KVws, Vtw, Pws, Qws);

    attn_kernel<<<512, 256, 0, stream>>>(Qws, KVws, Vtw, bias, mask_c, Cws);

    gemm_o_kernel<<<256, 512, 0, stream>>>(Cws, WTo, Pws);
    reduce_o_kernel<<<(M_ * D_) / 1024, 256, 0, stream>>>(Pws, out);
}

// Round 15
// 496.137 us; speedup vs baseline: 1.1908x; 1.1908x over previous
//
#include <hip/hip_runtime.h>
#include <stdint.h>

// ---------------------------------------------------------------------------
// CPMAntAttention: B=2,S=1024,D=4096,H=32,DH=128
// Round 15: revert attn to r13 (r14's 2-q-tile doubling spilled: 276MB scratch
// writes, MfmaUtil 6%). Keep r14's launch fusions (canon+detect, vt+reduce_q).
// GEMMs identical to r13 (10-slot ring core, homogeneous rounds).
// attn r12/r13 structure is a sharp local optimum: register budget exactly
// balanced; any added per-thread state spills (r7, r11, r14 all lost to it).
// ---------------------------------------------------------------------------

#define B_  2
#define S_  1024
#define D_  4096
#define H_  32
#define DH_ 128
#define M_  (B_ * S_)          // 2048
#define KSTR 8192              // row stride of fused KV output

typedef __attribute__((ext_vector_type(8))) short bf16x8;
typedef __attribute__((ext_vector_type(8))) unsigned short u16x8;
typedef __attribute__((ext_vector_type(4))) float f32x4;

static __device__ __forceinline__ unsigned short f32_to_bf16(float f) {
    unsigned int x = __float_as_uint(f);
    x += 0x7fffu + ((x >> 16) & 1u);   // RNE
    return (unsigned short)(x >> 16);
}

static __device__ __forceinline__ f32x4 mfma16(bf16x8 a, bf16x8 b, f32x4 c) {
    return __builtin_amdgcn_mfma_f32_16x16x32_bf16(a, b, c, 0, 0, 0);
}

#if defined(__has_builtin)
#if __has_builtin(__builtin_amdgcn_global_load_lds)
#define HAVE_GLOAD_LDS 1
#endif
#endif

#ifdef HAVE_GLOAD_LDS
#define GLD16(g, lbase, lane)                                                  \
    __builtin_amdgcn_global_load_lds(                                          \
        (const __attribute__((address_space(1))) void*)(g),                    \
        (__attribute__((address_space(3))) void*)(lbase), 16, 0, 0)
#else
#define GLD16(g, lbase, lane)                                                  \
    do { *(bf16x8*)((unsigned short*)(lbase) + (size_t)(lane) * 8) =           \
             *(const bf16x8*)(g); } while (0)
#endif

// ---------------------------------------------------------------------------
// canon_mask with inline dtype detection. 0=u8/bool, 1=int32, 2=float32.
__global__ void canon_mask_kernel(const void* __restrict__ m,
                                  unsigned char* __restrict__ out, int n) {
    __shared__ int sflag;
    int t = threadIdx.x;
    if (t < 64) {
        uint4 v = ((const uint4*)m)[t];
        unsigned int ww[4] = {v.x, v.y, v.z, v.w};
        int nz_hi = 0, nz_lo01 = 0;
#pragma unroll
        for (int wi = 0; wi < 4; ++wi)
#pragma unroll
            for (int bi = 0; bi < 4; ++bi) {
                unsigned int byte = (ww[wi] >> (bi * 8)) & 0xffu;
                if (byte && bi != 0) nz_hi = 1;
                if (byte && bi <= 1) nz_lo01 = 1;
            }
        int any_hi = __any(nz_hi);
        int any_lo01 = __any(nz_lo01);
        if (t == 0) sflag = (!any_hi) ? 1 : ((!any_lo01) ? 2 : 0);
    }
    __syncthreads();
    int f = sflag;
    int i = blockIdx.x * 256 + t;
    if (i >= n) return;
    unsigned char v;
    if (f == 1)      v = (unsigned char)(((const int*)m)[i] != 0);
    else if (f == 2) v = (unsigned char)(((const float*)m)[i] != 0.0f);
    else             v = (unsigned char)(((const unsigned char*)m)[i] != 0);
    out[i] = v;
}

__global__ void cvt2_bf16_kernel(const float* __restrict__ a, const float* __restrict__ b,
                                 unsigned short* __restrict__ oa, unsigned short* __restrict__ ob) {
    int i = blockIdx.x * 256 + threadIdx.x;
    const int n4 = (B_ * S_ * D_) / 4;
    const float* src = (i < n4) ? a : b;
    unsigned short* dst = (i < n4) ? oa : ob;
    int j = (i < n4) ? i : i - n4;
    float4 v = ((const float4*)src)[j];
    ushort4 o;
    o.x = f32_to_bf16(v.x); o.y = f32_to_bf16(v.y);
    o.z = f32_to_bf16(v.z); o.w = f32_to_bf16(v.w);
    ((ushort4*)dst)[j] = o;
}

// W [4096][4096] fp32 -> WT [n][k] bf16; 64x64 tiles; 16B/lane writes.
__global__ __launch_bounds__(256) void transpose_all_kernel(
        const float* __restrict__ Wq, const float* __restrict__ Wk,
        const float* __restrict__ Wv, const float* __restrict__ Wo,
        unsigned short* __restrict__ WTq, unsigned short* __restrict__ WTkv,
        unsigned short* __restrict__ WTo) {
    __shared__ unsigned short lds[64][65];
    int which = blockIdx.x >> 12;
    int bid = blockIdx.x & 4095;
    const float* W = (which == 0) ? Wq : (which == 1) ? Wk : (which == 2) ? Wv : Wo;
    unsigned short* WT = (which == 0) ? WTq
                       : (which == 1) ? WTkv
                       : (which == 2) ? (WTkv + (size_t)4096 * 4096)
                                      : WTo;
    int bx = bid & 63;
    int by = bid >> 6;
    int t = threadIdx.x;
    int tr = t >> 4;
    int tc = (t & 15) * 4;
#pragma unroll
    for (int p = 0; p < 4; ++p) {
        int r = p * 16 + tr;
        float4 v = *(const float4*)(W + (size_t)(by * 64 + r) * D_ + bx * 64 + tc);
        lds[r][tc + 0] = f32_to_bf16(v.x);
        lds[r][tc + 1] = f32_to_bf16(v.y);
        lds[r][tc + 2] = f32_to_bf16(v.z);
        lds[r][tc + 3] = f32_to_bf16(v.w);
    }
    __syncthreads();
    int wn = t >> 3;
    int k0 = (t & 7) * 8;
#pragma unroll
    for (int p2 = 0; p2 < 2; ++p2) {
        int n = p2 * 32 + wn;
        u16x8 o;
#pragma unroll
        for (int j = 0; j < 8; ++j) o[j] = lds[k0 + j][n];
        *(u16x8*)(WT + (size_t)(bx * 64 + n) * D_ + by * 64 + k0) = o;
    }
}

// Fused: bid<2048 -> V-transpose; else reduce_q (independent, concurrent).
__global__ __launch_bounds__(256) void vtrq_kernel(const unsigned short* __restrict__ KV,
                                                   unsigned short* __restrict__ Vtw,
                                                   const float* __restrict__ P,
                                                   unsigned short* __restrict__ Qout) {
    __shared__ unsigned short lds[64][72];
    int bid = blockIdx.x;
    int t = threadIdx.x;
    if (bid < 2048) {
        int dt = bid & 1;
        int st = (bid >> 1) & 15;
        int h  = (bid >> 5) & 31;
        int b  = bid >> 10;
        int r = t >> 2;
        int c0 = (t & 3) * 16;
        const unsigned short* src =
            KV + (size_t)(b * S_ + st * 64 + r) * KSTR + 4096 + h * DH_ + dt * 64 + c0;
        bf16x8 v0 = *(const bf16x8*)(src);
        bf16x8 v1 = *(const bf16x8*)(src + 8);
        *(bf16x8*)&lds[r][c0] = v0;
        *(bf16x8*)&lds[r][c0 + 8] = v1;
        __syncthreads();
        unsigned short tmp[16];
#pragma unroll
        for (int i = 0; i < 16; ++i) tmp[i] = lds[c0 + i][r];
        unsigned short* dst =
            Vtw + ((size_t)((b * H_ + h) * DH_ + dt * 64 + r)) * S_ + st * 64 + c0;
        *(bf16x8*)dst = *(bf16x8*)&tmp[0];
        *(bf16x8*)(dst + 8) = *(bf16x8*)&tmp[8];
    } else {
        int i = (bid - 2048) * 256 + t;
        float4 a = ((const float4*)P)[i];
        float4 b = ((const float4*)(P + (size_t)M_ * D_))[i];
        ushort4 o;
        o.x = f32_to_bf16(a.x + b.x); o.y = f32_to_bf16(a.y + b.y);
        o.z = f32_to_bf16(a.z + b.z); o.w = f32_to_bf16(a.w + b.w);
        ((ushort4*)Qout)[i] = o;
    }
}

// ---------------------------------------------------------------------------
// Phase-pipelined GEMM core (r13): 10-slot ring (160 KiB), prefetch dist 6,
// vmcnt(4) steady / vmcnt(0) final tile. Tile 256x256, BK=64, 512 thr.
__device__ __forceinline__ void gemm_core(const unsigned short* __restrict__ A,
                                          const unsigned short* __restrict__ BT,
                                          void* __restrict__ C, int out_f32,
                                          int m0, int n0, int cstride,
                                          int koff, int NT, char* ldsc) {
    const int t = threadIdx.x;
    const int w = t >> 6, l = t & 63;
    const int lr = l & 15, lg = l >> 4;
    const int wmh = w >> 2;
    const int walf = w & 3;
    const int wm = wmh << 7;
    const int wn = walf << 6;

    const int ca0 = lg ^ (lr & 7);
    const int aoff0 = lr * 128 + (ca0 << 4);
    const int aoff1 = lr * 128 + ((ca0 ^ 4) << 4);
    const int boff0 = ((walf & 1) * 64 + lr) * 128 + (ca0 << 4);
    const int boff1 = ((walf & 1) * 64 + lr) * 128 + ((ca0 ^ 4) << 4);

    const int srow = t >> 3;
    const int sch = (t & 7) ^ (srow & 7);
    const size_t soff0 = (size_t)srow * 4096 + (size_t)(sch << 3);
    const size_t soff1 = soff0 + (size_t)64 * 4096;
    const int ldso = w << 10;

    f32x4 ac[8][4];
    f32x4 vzero = {0.f, 0.f, 0.f, 0.f};
#pragma unroll
    for (int i = 0; i < 8; ++i)
#pragma unroll
        for (int j = 0; j < 4; ++j) ac[i][j] = vzero;

#define STAGE_ELEM(E, SS)                                                      \
    do {                                                                       \
        int er_ = (E) & 3;                                                     \
        const unsigned short* mb_ = (er_ < 2)                                  \
            ? A + (size_t)(m0 + ((er_ & 1) << 7)) * 4096                       \
            : BT + (size_t)(n0 + ((er_ & 1) << 7)) * 4096;                     \
        mb_ += (size_t)((((E) >> 2) << 6) + koff);                             \
        char* d0_ = ldsc + (SS) * 16384 + ldso;                                \
        GLD16(mb_ + soff0, d0_, l);                                            \
        GLD16(mb_ + soff1, d0_ + 8192, l);                                     \
    } while (0)

#pragma unroll
    for (int e = 0; e < 6; ++e) STAGE_ELEM(e, e);

    const int NT4 = NT << 2;
    int E = 6, ss = 6, s0 = 0;
    bf16x8 bfr[4][2];

#pragma unroll 1
    for (int tau = 0; tau < NT; ++tau) {
        int sA = s0 + wmh;             if (sA >= 10) sA -= 10;
        int sB = s0 + 2 + (walf >> 1); if (sB >= 10) sB -= 10;
        const char* pA0 = ldsc + sA * 16384 + aoff0;
        const char* pA1 = ldsc + sA * 16384 + aoff1;
        const char* pB0 = ldsc + sB * 16384 + boff0;
        const char* pB1 = ldsc + sB * 16384 + boff1;
#pragma unroll
        for (int r = 0; r < 4; ++r) {
            if (r == 0) {
                if (tau == NT - 1)
                    asm volatile("s_waitcnt vmcnt(0)" ::: "memory");
                else
                    asm volatile("s_waitcnt vmcnt(4)" ::: "memory");
            }
            __builtin_amdgcn_s_barrier();
            asm volatile("" ::: "memory");
            if (r == 0) {
#pragma unroll
                for (int nf = 0; nf < 4; ++nf) {
                    bfr[nf][0] = *(const bf16x8*)(pB0 + nf * 2048);
                    bfr[nf][1] = *(const bf16x8*)(pB1 + nf * 2048);
                }
            }
            bf16x8 af[2][2];
            int mfb = r << 1;
#pragma unroll
            for (int j = 0; j < 2; ++j) {
                af[j][0] = *(const bf16x8*)(pA0 + (mfb + j) * 2048);
                af[j][1] = *(const bf16x8*)(pA1 + (mfb + j) * 2048);
            }
            if (E < NT4) STAGE_ELEM(E, ss);
            ++E; ss = (ss == 9) ? 0 : ss + 1;
            __builtin_amdgcn_s_setprio(1);
#pragma unroll
            for (int j = 0; j < 2; ++j)
#pragma unroll
                for (int nf = 0; nf < 4; ++nf) {
                    ac[mfb + j][nf] = mfma16(af[j][0], bfr[nf][0], ac[mfb + j][nf]);
                    ac[mfb + j][nf] = mfma16(af[j][1], bfr[nf][1], ac[mfb + j][nf]);
                }
            __builtin_amdgcn_s_setprio(0);
        }
        s0 += 4; if (s0 >= 10) s0 -= 10;
    }
#undef STAGE_ELEM

#pragma unroll
    for (int mf = 0; mf < 8; ++mf)
#pragma unroll
        for (int nf = 0; nf < 4; ++nf)
#pragma unroll
            for (int q = 0; q < 4; ++q) {
                int row = m0 + wm + mf * 16 + lg * 4 + q;
                int col = n0 + wn + nf * 16 + lr;
                if (out_f32)
                    ((float*)C)[(size_t)row * cstride + col] = ac[mf][nf][q];
                else
                    ((unsigned short*)C)[(size_t)row * cstride + col] = f32_to_bf16(ac[mf][nf][q]);
            }
}

// 512 blocks, two homogeneous rounds: 0..255 KV full-K, 256..511 Q splitK2.
__global__ __launch_bounds__(512, 1) void gemm_qkv_kernel(
        const unsigned short* __restrict__ Aq, const unsigned short* __restrict__ Bq,
        float* __restrict__ Pq,
        const unsigned short* __restrict__ Akv, const unsigned short* __restrict__ Bkv,
        unsigned short* __restrict__ Ckv) {
    __shared__ char ldsbuf[10 * 16384];
    int bid = blockIdx.x;
    if (bid < 256) {
        int bm = bid & 7, bn = bid >> 3;
        gemm_core(Akv, Bkv, Ckv, 0, bm << 8, bn << 8, 8192, 0, 64, ldsbuf);
    } else {
        int e = bid - 256;
        int bm = e & 7;
        int rest = e >> 3;
        int bn = rest & 15;
        int ks = rest >> 4;
        gemm_core(Aq, Bq, Pq + (size_t)ks * M_ * D_, 1, bm << 8, bn << 8, 4096,
                  ks * 2048, 32, ldsbuf);
    }
}

__global__ __launch_bounds__(512, 1) void gemm_o_kernel(
        const unsigned short* __restrict__ A, const unsigned short* __restrict__ BT,
        float* __restrict__ P) {
    __shared__ char ldsbuf[10 * 16384];
    int bid = blockIdx.x;
    int bm = bid & 7;
    int rest = bid >> 3;
    int bn = rest & 15;
    int ks = rest >> 4;
    gemm_core(A, BT, P + (size_t)ks * M_ * D_, 1, bm << 8, bn << 8, 4096,
              ks * 2048, 32, ldsbuf);
}

__global__ void reduce_o_kernel(const float* __restrict__ P, float* __restrict__ out) {
    int i = blockIdx.x * 256 + threadIdx.x;
    float4 a = ((const float4*)P)[i];
    float4 b = ((const float4*)(P + (size_t)M_ * D_))[i];
    float4 o; o.x = a.x + b.x; o.y = a.y + b.y; o.z = a.z + b.z; o.w = a.w + b.w;
    ((float4*)out)[i] = o;
}

// ---------------------------------------------------------------------------
// Flash attention (r13, proven local optimum): dbuf global_load_lds K/V,
// swapped QK^T, wide bias/mask loads, lane-local softmax, XCD grouping.
#define NEGF (-1e30f)
__global__ __launch_bounds__(256, 2) void attn_kernel(const unsigned short* __restrict__ Qw,
                                                      const unsigned short* __restrict__ KV,
                                                      const unsigned short* __restrict__ Vtw,
                                                      const float* __restrict__ bias,
                                                      const unsigned char* __restrict__ maskc,
                                                      unsigned short* __restrict__ ctx) {
    __shared__ unsigned short Kbuf[2][64 * 128];
    __shared__ unsigned short Vbuf[2][128 * 64];
    __shared__ unsigned short Plds[4][16 * 72];

    int x = blockIdx.x;
    int xcd = x & 7;
    int rest = x >> 3;           // 0..127
    int qt = rest & 15;
    int gq = rest >> 4;          // 0..7
    int g = gq * 8 + xcd;        // 0..63
    int b = g >> 5, h = g & 31;

    int t = threadIdx.x, w = t >> 6, l = t & 63;
    int lr = l & 15, lg = l >> 4;
    int q0 = (qt << 6) + (w << 4);

    bf16x8 qf[4];
    const unsigned short* Qp = Qw + ((size_t)(b * S_ + q0 + lr)) * D_ + h * DH_ + lg * 8;
#pragma unroll
    for (int kf = 0; kf < 4; ++kf) qf[kf] = *(const bf16x8*)(Qp + kf * 32);

    f32x4 o[8];
    f32x4 vzero = {0.f, 0.f, 0.f, 0.f};
#pragma unroll
    for (int i = 0; i < 8; ++i) o[i] = vzero;
    float m_run = NEGF, l_run = 0.f;     // per-lane: q-row = q0 + lr

    const float* biasp = bias + (((size_t)(b * H_ + h)) << 20)
                              + (((size_t)(q0 + lr)) << 10);
    const unsigned char* mp = maskc + ((size_t)b << 20)
                              + (((size_t)(q0 + lr)) << 10);
    const unsigned short* Kg = KV + (size_t)(b * S_) * KSTR + h * DH_;
    const unsigned short* Vg = Vtw + (((size_t)(b * H_ + h)) * DH_) * S_;

    float4 br0[4], br1[4];
    unsigned int mr0[4], mr1[4];

#define STAGE_KV(KT, BUF)                                                          \
    do { int kv0_ = (KT) << 6;                                                     \
        _Pragma("unroll")                                                          \
        for (int c = 0; c < 4; ++c) {                                              \
            int seg = (w << 2) + c;                                                \
            int krow = (seg << 2) + (l >> 4);                                      \
            int kch = (l & 15) ^ (krow & 7);                                       \
            GLD16(Kg + (size_t)(kv0_ + krow) * KSTR + (kch << 3),                  \
                  &Kbuf[BUF][seg << 9], l);                                        \
            int vrow = (seg << 3) + (l >> 3);                                      \
            int vch = (l & 7) ^ (vrow & 7);                                        \
            GLD16(Vg + (size_t)vrow * S_ + kv0_ + (vch << 3),                      \
                  &Vbuf[BUF][seg << 9], l);                                        \
        }                                                                          \
    } while (0)

#define LOAD_BM(BR, MR, KT)                                                        \
    do { int kv0_ = (KT) << 6;                                                     \
        _Pragma("unroll")                                                          \
        for (int nb = 0; nb < 4; ++nb) {                                           \
            BR[nb] = *(const float4*)(biasp + kv0_ + (nb << 4) + (lg << 2));       \
            MR[nb] = *(const unsigned int*)(mp + kv0_ + (nb << 4) + (lg << 2));    \
        }                                                                          \
    } while (0)

#define COMPUTE(BUF, BR, MR)                                                       \
    do {                                                                           \
        f32x4 s_[4];                                                               \
        __builtin_amdgcn_s_setprio(1);                                             \
        _Pragma("unroll")                                                          \
        for (int nb = 0; nb < 4; ++nb) {                                           \
            s_[nb] = vzero;                                                        \
            int krow = (nb << 4) + lr;                                             \
            _Pragma("unroll")                                                      \
            for (int kf = 0; kf < 4; ++kf) {                                       \
                int ba = ((krow << 8) + (((kf << 5) + (lg << 3)) << 1))            \
                         ^ ((krow & 7) << 4);                                      \
                bf16x8 kfr = *(const bf16x8*)((const char*)Kbuf[BUF] + ba);        \
                s_[nb] = mfma16(kfr, qf[kf], s_[nb]);                              \
            }                                                                      \
        }                                                                          \
        __builtin_amdgcn_s_setprio(0);                                             \
        float sv[4][4];                                                            \
        _Pragma("unroll")                                                          \
        for (int nb = 0; nb < 4; ++nb) {                                           \
            float bb[4] = {BR[nb].x, BR[nb].y, BR[nb].z, BR[nb].w};                \
            _Pragma("unroll")                                                      \
            for (int r = 0; r < 4; ++r) {                                          \
                float x2 = fmaf(s_[nb][r], 0.08838834764831845f, bb[r]);           \
                sv[nb][r] = ((MR[nb] >> (r * 8)) & 0xffu) ? x2 : NEGF;             \
            }                                                                      \
        }                                                                          \
        float mt = sv[0][0];                                                       \
        _Pragma("unroll")                                                          \
        for (int nb = 0; nb < 4; ++nb)                                             \
            _Pragma("unroll")                                                      \
            for (int r = 0; r < 4; ++r) mt = fmaxf(mt, sv[nb][r]);                 \
        mt = fmaxf(mt, __shfl_xor(mt, 16, 64));                                    \
        mt = fmaxf(mt, __shfl_xor(mt, 32, 64));                                    \
        float mn = fmaxf(m_run, mt);                                               \
        float al = __expf(m_run - mn);                                             \
        m_run = mn;                                                                \
        float rs = 0.f;                                                            \
        _Pragma("unroll")                                                          \
        for (int nb = 0; nb < 4; ++nb)                                             \
            _Pragma("unroll")                                                      \
            for (int r = 0; r < 4; ++r) {                                          \
                sv[nb][r] = __expf(sv[nb][r] - m_run);                             \
                rs += sv[nb][r];                                                   \
            }                                                                      \
        rs += __shfl_xor(rs, 16, 64);                                              \
        rs += __shfl_xor(rs, 32, 64);                                              \
        l_run = l_run * al + rs;                                                   \
        float alm[4];                                                              \
        _Pragma("unroll")                                                          \
        for (int r = 0; r < 4; ++r) alm[r] = __shfl(al, (lg << 2) + r, 64);        \
        _Pragma("unroll")                                                          \
        for (int nb2 = 0; nb2 < 8; ++nb2) {                                        \
            o[nb2][0] *= alm[0]; o[nb2][1] *= alm[1];                              \
            o[nb2][2] *= alm[2]; o[nb2][3] *= alm[3];                              \
        }                                                                          \
        _Pragma("unroll")                                                          \
        for (int nb = 0; nb < 4; ++nb)                                             \
            _Pragma("unroll")                                                      \
            for (int r = 0; r < 4; ++r)                                            \
                Plds[w][lr * 72 + (nb << 4) + (lg << 2) + r] = f32_to_bf16(sv[nb][r]); \
        __builtin_amdgcn_s_setprio(1);                                             \
        _Pragma("unroll")                                                          \
        for (int kf2 = 0; kf2 < 2; ++kf2) {                                        \
            bf16x8 pf = *(const bf16x8*)&Plds[w][lr * 72 + (kf2 << 5) + (lg << 3)]; \
            _Pragma("unroll")                                                      \
            for (int nb2 = 0; nb2 < 8; ++nb2) {                                    \
                int dh = (nb2 << 4) + lr;                                          \
                int ba = ((dh << 7) + (((kf2 << 5) + (lg << 3)) << 1))             \
                         ^ ((dh & 7) << 4);                                        \
                bf16x8 vf = *(const bf16x8*)((const char*)Vbuf[BUF] + ba);         \
                o[nb2] = mfma16(pf, vf, o[nb2]);                                   \
            }                                                                      \
        }                                                                          \
        __builtin_amdgcn_s_setprio(0);                                             \
    } while (0)

    STAGE_KV(0, 0);
    LOAD_BM(br0, mr0, 0);

#pragma unroll 1
    for (int kt = 0; kt < 16; kt += 2) {
        __syncthreads();
        STAGE_KV(kt + 1, 1);
        LOAD_BM(br1, mr1, kt + 1);
        COMPUTE(0, br0, mr0);
        __syncthreads();
        if (kt < 14) {
            STAGE_KV(kt + 2, 0);
            LOAD_BM(br0, mr0, kt + 2);
        }
        COMPUTE(1, br1, mr1);
    }

    float lm[4];
#pragma unroll
    for (int r = 0; r < 4; ++r) lm[r] = __shfl(l_run, (lg << 2) + r, 64);
#pragma unroll
    for (int r = 0; r < 4; ++r) {
        float inv = lm[r] > 0.f ? 1.0f / lm[r] : 0.f;
        int q = q0 + (lg << 2) + r;
        unsigned short* cp = ctx + ((size_t)(b * S_ + q)) * D_ + h * DH_ + lr;
#pragma unroll
        for (int nb2 = 0; nb2 < 8; ++nb2)
            cp[nb2 * 16] = f32_to_bf16(o[nb2][r] * inv);
    }
#undef STAGE_KV
#undef LOAD_BM
#undef COMPUTE
}

// ---------------------------------------------------------------------------
extern "C" void kernel_launch(void* const* d_in, const int* in_sizes, int n_in,
                              void* d_out, int out_size, void* d_ws, size_t ws_size,
                              hipStream_t stream) {
    const float* hq   = (const float*)d_in[0];
    const float* hkv  = (const float*)d_in[1];
    const void*  mask = d_in[2];
    const float* bias = (const float*)d_in[3];
    const float* Wq   = (const float*)d_in[4];
    const float* Wk   = (const float*)d_in[5];
    const float* Wv   = (const float*)d_in[6];
    const float* Wo   = (const float*)d_in[7];
    float* out = (float*)d_out;

    char* ws = (char*)d_ws;
    unsigned char* mask_c = (unsigned char*)ws;                        // 2 MB
    unsigned short* hq_b  = (unsigned short*)(ws + (2u << 20) + 4096); // 16 MB
    unsigned short* hkv_b = hq_b + ((size_t)1 << 23);                  // 16 MB
    unsigned short* WTq   = hkv_b + ((size_t)1 << 23);                 // 32 MB
    unsigned short* WTo   = WTq + ((size_t)1 << 24);                   // 32 MB
    unsigned short* WTkv  = WTo + ((size_t)1 << 24);                   // 64 MB
    unsigned short* Qws   = WTkv + ((size_t)1 << 25);                  // 16 MB
    unsigned short* KVws  = Qws + ((size_t)1 << 23);                   // 32 MB
    unsigned short* Cws   = KVws + ((size_t)1 << 24);                  // 16 MB
    unsigned short* Vtw   = Cws + ((size_t)1 << 23);                   // 16 MB
    float* Pws            = (float*)(Vtw + ((size_t)1 << 23));         // 64 MB

    canon_mask_kernel<<<8192, 256, 0, stream>>>(mask, mask_c, B_ * S_ * S_);
    cvt2_bf16_kernel<<<16384, 256, 0, stream>>>(hq, hkv, hq_b, hkv_b);
    transpose_all_kernel<<<16384, 256, 0, stream>>>(Wq, Wk, Wv, Wo, WTq, WTkv, WTo);

    gemm_qkv_kernel<<<512, 512, 0, stream>>>(hq_b, WTq, Pws, hkv_b, WTkv, KVws);
    vtrq_kernel<<<10240, 256, 0, stream>>>(KVws, Vtw, Pws, Qws);

    attn_kernel<<<B_ * H_ * (S_ / 64), 256, 0, stream>>>(Qws, KVws, Vtw, bias, mask_c, Cws);

    gemm_o_kernel<<<256, 512, 0, stream>>>(Cws, WTo, Pws);
    reduce_o_kernel<<<(M_ * D_) / 1024, 256, 0, stream>>>(Pws, out);
}

// Round 16
// 488.614 us; speedup vs baseline: 1.2091x; 1.0154x over previous
//
#include <hip/hip_runtime.h>
#include <stdint.h>

// ---------------------------------------------------------------------------
// CPMAntAttention: B=2,S=1024,D=4096,H=32,DH=128
// Round 16: fuse the three independent prep kernels (canon_mask, cvt2,
// transpose_all) into one 40960-block launch (grid-disjoint branches, same
// pattern as vtrq). 6 total launches. Everything else identical to r15 best:
// 10-slot-ring GEMM core, homogeneous qkv rounds, r13 attn, vtrq fusion.
// ---------------------------------------------------------------------------

#define B_  2
#define S_  1024
#define D_  4096
#define H_  32
#define DH_ 128
#define M_  (B_ * S_)          // 2048
#define KSTR 8192              // row stride of fused KV output

typedef __attribute__((ext_vector_type(8))) short bf16x8;
typedef __attribute__((ext_vector_type(8))) unsigned short u16x8;
typedef __attribute__((ext_vector_type(4))) float f32x4;

static __device__ __forceinline__ unsigned short f32_to_bf16(float f) {
    unsigned int x = __float_as_uint(f);
    x += 0x7fffu + ((x >> 16) & 1u);   // RNE
    return (unsigned short)(x >> 16);
}

static __device__ __forceinline__ f32x4 mfma16(bf16x8 a, bf16x8 b, f32x4 c) {
    return __builtin_amdgcn_mfma_f32_16x16x32_bf16(a, b, c, 0, 0, 0);
}

#if defined(__has_builtin)
#if __has_builtin(__builtin_amdgcn_global_load_lds)
#define HAVE_GLOAD_LDS 1
#endif
#endif

#ifdef HAVE_GLOAD_LDS
#define GLD16(g, lbase, lane)                                                  \
    __builtin_amdgcn_global_load_lds(                                          \
        (const __attribute__((address_space(1))) void*)(g),                    \
        (__attribute__((address_space(3))) void*)(lbase), 16, 0, 0)
#else
#define GLD16(g, lbase, lane)                                                  \
    do { *(bf16x8*)((unsigned short*)(lbase) + (size_t)(lane) * 8) =           \
             *(const bf16x8*)(g); } while (0)
#endif

// ---------------------------------------------------------------------------
// Fused prep: blocks 0..16383 transpose_all | 16384..24575 canon_mask |
// 24576..40959 cvt2. All branches independent (distinct in->out).
__global__ __launch_bounds__(256) void prep_kernel(
        const float* __restrict__ Wq, const float* __restrict__ Wk,
        const float* __restrict__ Wv, const float* __restrict__ Wo,
        unsigned short* __restrict__ WTq, unsigned short* __restrict__ WTkv,
        unsigned short* __restrict__ WTo,
        const void* __restrict__ mask, unsigned char* __restrict__ mask_c,
        const float* __restrict__ hq, const float* __restrict__ hkv,
        unsigned short* __restrict__ hq_b, unsigned short* __restrict__ hkv_b) {
    __shared__ unsigned short lds[64][65];
    __shared__ int sflag;
    int gbid = blockIdx.x;
    int t = threadIdx.x;

    if (gbid < 16384) {
        // ---- transpose_all: W [4096][4096] fp32 -> WT [n][k] bf16
        int which = gbid >> 12;
        int bid = gbid & 4095;
        const float* W = (which == 0) ? Wq : (which == 1) ? Wk : (which == 2) ? Wv : Wo;
        unsigned short* WT = (which == 0) ? WTq
                           : (which == 1) ? WTkv
                           : (which == 2) ? (WTkv + (size_t)4096 * 4096)
                                          : WTo;
        int bx = bid & 63;
        int by = bid >> 6;
        int tr = t >> 4;
        int tc = (t & 15) * 4;
#pragma unroll
        for (int p = 0; p < 4; ++p) {
            int r = p * 16 + tr;
            float4 v = *(const float4*)(W + (size_t)(by * 64 + r) * D_ + bx * 64 + tc);
            lds[r][tc + 0] = f32_to_bf16(v.x);
            lds[r][tc + 1] = f32_to_bf16(v.y);
            lds[r][tc + 2] = f32_to_bf16(v.z);
            lds[r][tc + 3] = f32_to_bf16(v.w);
        }
        __syncthreads();
        int wn = t >> 3;
        int k0 = (t & 7) * 8;
#pragma unroll
        for (int p2 = 0; p2 < 2; ++p2) {
            int n = p2 * 32 + wn;
            u16x8 o;
#pragma unroll
            for (int j = 0; j < 8; ++j) o[j] = lds[k0 + j][n];
            *(u16x8*)(WT + (size_t)(bx * 64 + n) * D_ + by * 64 + k0) = o;
        }
    } else if (gbid < 24576) {
        // ---- canon_mask with inline dtype detection
        if (t < 64) {
            uint4 v = ((const uint4*)mask)[t];
            unsigned int ww[4] = {v.x, v.y, v.z, v.w};
            int nz_hi = 0, nz_lo01 = 0;
#pragma unroll
            for (int wi = 0; wi < 4; ++wi)
#pragma unroll
                for (int bi = 0; bi < 4; ++bi) {
                    unsigned int byte = (ww[wi] >> (bi * 8)) & 0xffu;
                    if (byte && bi != 0) nz_hi = 1;
                    if (byte && bi <= 1) nz_lo01 = 1;
                }
            int any_hi = __any(nz_hi);
            int any_lo01 = __any(nz_lo01);
            if (t == 0) sflag = (!any_hi) ? 1 : ((!any_lo01) ? 2 : 0);
        }
        __syncthreads();
        int f = sflag;
        int i = (gbid - 16384) * 256 + t;
        unsigned char v;
        if (f == 1)      v = (unsigned char)(((const int*)mask)[i] != 0);
        else if (f == 2) v = (unsigned char)(((const float*)mask)[i] != 0.0f);
        else             v = (unsigned char)(((const unsigned char*)mask)[i] != 0);
        mask_c[i] = v;
    } else {
        // ---- cvt2: fp32 -> bf16 for both hidden tensors
        int i = (gbid - 24576) * 256 + t;
        const int n4 = (B_ * S_ * D_) / 4;       // 2M float4 per tensor
        const float* src = (i < n4) ? hq : hkv;
        unsigned short* dst = (i < n4) ? hq_b : hkv_b;
        int j = (i < n4) ? i : i - n4;
        float4 v = ((const float4*)src)[j];
        ushort4 o;
        o.x = f32_to_bf16(v.x); o.y = f32_to_bf16(v.y);
        o.z = f32_to_bf16(v.z); o.w = f32_to_bf16(v.w);
        ((ushort4*)dst)[j] = o;
    }
}

// Fused: bid<2048 -> V-transpose; else reduce_q (independent, concurrent).
__global__ __launch_bounds__(256) void vtrq_kernel(const unsigned short* __restrict__ KV,
                                                   unsigned short* __restrict__ Vtw,
                                                   const float* __restrict__ P,
                                                   unsigned short* __restrict__ Qout) {
    __shared__ unsigned short lds[64][72];
    int bid = blockIdx.x;
    int t = threadIdx.x;
    if (bid < 2048) {
        int dt = bid & 1;
        int st = (bid >> 1) & 15;
        int h  = (bid >> 5) & 31;
        int b  = bid >> 10;
        int r = t >> 2;
        int c0 = (t & 3) * 16;
        const unsigned short* src =
            KV + (size_t)(b * S_ + st * 64 + r) * KSTR + 4096 + h * DH_ + dt * 64 + c0;
        bf16x8 v0 = *(const bf16x8*)(src);
        bf16x8 v1 = *(const bf16x8*)(src + 8);
        *(bf16x8*)&lds[r][c0] = v0;
        *(bf16x8*)&lds[r][c0 + 8] = v1;
        __syncthreads();
        unsigned short tmp[16];
#pragma unroll
        for (int i = 0; i < 16; ++i) tmp[i] = lds[c0 + i][r];
        unsigned short* dst =
            Vtw + ((size_t)((b * H_ + h) * DH_ + dt * 64 + r)) * S_ + st * 64 + c0;
        *(bf16x8*)dst = *(bf16x8*)&tmp[0];
        *(bf16x8*)(dst + 8) = *(bf16x8*)&tmp[8];
    } else {
        int i = (bid - 2048) * 256 + t;
        float4 a = ((const float4*)P)[i];
        float4 b = ((const float4*)(P + (size_t)M_ * D_))[i];
        ushort4 o;
        o.x = f32_to_bf16(a.x + b.x); o.y = f32_to_bf16(a.y + b.y);
        o.z = f32_to_bf16(a.z + b.z); o.w = f32_to_bf16(a.w + b.w);
        ((ushort4*)Qout)[i] = o;
    }
}

// ---------------------------------------------------------------------------
// Phase-pipelined GEMM core (r13): 10-slot ring (160 KiB), prefetch dist 6,
// vmcnt(4) steady / vmcnt(0) final tile. Tile 256x256, BK=64, 512 thr.
__device__ __forceinline__ void gemm_core(const unsigned short* __restrict__ A,
                                          const unsigned short* __restrict__ BT,
                                          void* __restrict__ C, int out_f32,
                                          int m0, int n0, int cstride,
                                          int koff, int NT, char* ldsc) {
    const int t = threadIdx.x;
    const int w = t >> 6, l = t & 63;
    const int lr = l & 15, lg = l >> 4;
    const int wmh = w >> 2;
    const int walf = w & 3;
    const int wm = wmh << 7;
    const int wn = walf << 6;

    const int ca0 = lg ^ (lr & 7);
    const int aoff0 = lr * 128 + (ca0 << 4);
    const int aoff1 = lr * 128 + ((ca0 ^ 4) << 4);
    const int boff0 = ((walf & 1) * 64 + lr) * 128 + (ca0 << 4);
    const int boff1 = ((walf & 1) * 64 + lr) * 128 + ((ca0 ^ 4) << 4);

    const int srow = t >> 3;
    const int sch = (t & 7) ^ (srow & 7);
    const size_t soff0 = (size_t)srow * 4096 + (size_t)(sch << 3);
    const size_t soff1 = soff0 + (size_t)64 * 4096;
    const int ldso = w << 10;

    f32x4 ac[8][4];
    f32x4 vzero = {0.f, 0.f, 0.f, 0.f};
#pragma unroll
    for (int i = 0; i < 8; ++i)
#pragma unroll
        for (int j = 0; j < 4; ++j) ac[i][j] = vzero;

#define STAGE_ELEM(E, SS)                                                      \
    do {                                                                       \
        int er_ = (E) & 3;                                                     \
        const unsigned short* mb_ = (er_ < 2)                                  \
            ? A + (size_t)(m0 + ((er_ & 1) << 7)) * 4096                       \
            : BT + (size_t)(n0 + ((er_ & 1) << 7)) * 4096;                     \
        mb_ += (size_t)((((E) >> 2) << 6) + koff);                             \
        char* d0_ = ldsc + (SS) * 16384 + ldso;                                \
        GLD16(mb_ + soff0, d0_, l);                                            \
        GLD16(mb_ + soff1, d0_ + 8192, l);                                     \
    } while (0)

#pragma unroll
    for (int e = 0; e < 6; ++e) STAGE_ELEM(e, e);

    const int NT4 = NT << 2;
    int E = 6, ss = 6, s0 = 0;
    bf16x8 bfr[4][2];

#pragma unroll 1
    for (int tau = 0; tau < NT; ++tau) {
        int sA = s0 + wmh;             if (sA >= 10) sA -= 10;
        int sB = s0 + 2 + (walf >> 1); if (sB >= 10) sB -= 10;
        const char* pA0 = ldsc + sA * 16384 + aoff0;
        const char* pA1 = ldsc + sA * 16384 + aoff1;
        const char* pB0 = ldsc + sB * 16384 + boff0;
        const char* pB1 = ldsc + sB * 16384 + boff1;
#pragma unroll
        for (int r = 0; r < 4; ++r) {
            if (r == 0) {
                if (tau == NT - 1)
                    asm volatile("s_waitcnt vmcnt(0)" ::: "memory");
                else
                    asm volatile("s_waitcnt vmcnt(4)" ::: "memory");
            }
            __builtin_amdgcn_s_barrier();
            asm volatile("" ::: "memory");
            if (r == 0) {
#pragma unroll
                for (int nf = 0; nf < 4; ++nf) {
                    bfr[nf][0] = *(const bf16x8*)(pB0 + nf * 2048);
                    bfr[nf][1] = *(const bf16x8*)(pB1 + nf * 2048);
                }
            }
            bf16x8 af[2][2];
            int mfb = r << 1;
#pragma unroll
            for (int j = 0; j < 2; ++j) {
                af[j][0] = *(const bf16x8*)(pA0 + (mfb + j) * 2048);
                af[j][1] = *(const bf16x8*)(pA1 + (mfb + j) * 2048);
            }
            if (E < NT4) STAGE_ELEM(E, ss);
            ++E; ss = (ss == 9) ? 0 : ss + 1;
            __builtin_amdgcn_s_setprio(1);
#pragma unroll
            for (int j = 0; j < 2; ++j)
#pragma unroll
                for (int nf = 0; nf < 4; ++nf) {
                    ac[mfb + j][nf] = mfma16(af[j][0], bfr[nf][0], ac[mfb + j][nf]);
                    ac[mfb + j][nf] = mfma16(af[j][1], bfr[nf][1], ac[mfb + j][nf]);
                }
            __builtin_amdgcn_s_setprio(0);
        }
        s0 += 4; if (s0 >= 10) s0 -= 10;
    }
#undef STAGE_ELEM

#pragma unroll
    for (int mf = 0; mf < 8; ++mf)
#pragma unroll
        for (int nf = 0; nf < 4; ++nf)
#pragma unroll
            for (int q = 0; q < 4; ++q) {
                int row = m0 + wm + mf * 16 + lg * 4 + q;
                int col = n0 + wn + nf * 16 + lr;
                if (out_f32)
                    ((float*)C)[(size_t)row * cstride + col] = ac[mf][nf][q];
                else
                    ((unsigned short*)C)[(size_t)row * cstride + col] = f32_to_bf16(ac[mf][nf][q]);
            }
}

// 512 blocks, two homogeneous rounds: 0..255 KV full-K, 256..511 Q splitK2.
__global__ __launch_bounds__(512, 1) void gemm_qkv_kernel(
        const unsigned short* __restrict__ Aq, const unsigned short* __restrict__ Bq,
        float* __restrict__ Pq,
        const unsigned short* __restrict__ Akv, const unsigned short* __restrict__ Bkv,
        unsigned short* __restrict__ Ckv) {
    __shared__ char ldsbuf[10 * 16384];
    int bid = blockIdx.x;
    if (bid < 256) {
        int bm = bid & 7, bn = bid >> 3;
        gemm_core(Akv, Bkv, Ckv, 0, bm << 8, bn << 8, 8192, 0, 64, ldsbuf);
    } else {
        int e = bid - 256;
        int bm = e & 7;
        int rest = e >> 3;
        int bn = rest & 15;
        int ks = rest >> 4;
        gemm_core(Aq, Bq, Pq + (size_t)ks * M_ * D_, 1, bm << 8, bn << 8, 4096,
                  ks * 2048, 32, ldsbuf);
    }
}

__global__ __launch_bounds__(512, 1) void gemm_o_kernel(
        const unsigned short* __restrict__ A, const unsigned short* __restrict__ BT,
        float* __restrict__ P) {
    __shared__ char ldsbuf[10 * 16384];
    int bid = blockIdx.x;
    int bm = bid & 7;
    int rest = bid >> 3;
    int bn = rest & 15;
    int ks = rest >> 4;
    gemm_core(A, BT, P + (size_t)ks * M_ * D_, 1, bm << 8, bn << 8, 4096,
              ks * 2048, 32, ldsbuf);
}

__global__ void reduce_o_kernel(const float* __restrict__ P, float* __restrict__ out) {
    int i = blockIdx.x * 256 + threadIdx.x;
    float4 a = ((const float4*)P)[i];
    float4 b = ((const float4*)(P + (size_t)M_ * D_))[i];
    float4 o; o.x = a.x + b.x; o.y = a.y + b.y; o.z = a.z + b.z; o.w = a.w + b.w;
    ((float4*)out)[i] = o;
}

// ---------------------------------------------------------------------------
// Flash attention (r13, proven local optimum): dbuf global_load_lds K/V,
// swapped QK^T, wide bias/mask loads, lane-local softmax, XCD grouping.
#define NEGF (-1e30f)
__global__ __launch_bounds__(256, 2) void attn_kernel(const unsigned short* __restrict__ Qw,
                                                      const unsigned short* __restrict__ KV,
                                                      const unsigned short* __restrict__ Vtw,
                                                      const float* __restrict__ bias,
                                                      const unsigned char* __restrict__ maskc,
                                                      unsigned short* __restrict__ ctx) {
    __shared__ unsigned short Kbuf[2][64 * 128];
    __shared__ unsigned short Vbuf[2][128 * 64];
    __shared__ unsigned short Plds[4][16 * 72];

    int x = blockIdx.x;
    int xcd = x & 7;
    int rest = x >> 3;           // 0..127
    int qt = rest & 15;
    int gq = rest >> 4;          // 0..7
    int g = gq * 8 + xcd;        // 0..63
    int b = g >> 5, h = g & 31;

    int t = threadIdx.x, w = t >> 6, l = t & 63;
    int lr = l & 15, lg = l >> 4;
    int q0 = (qt << 6) + (w << 4);

    bf16x8 qf[4];
    const unsigned short* Qp = Qw + ((size_t)(b * S_ + q0 + lr)) * D_ + h * DH_ + lg * 8;
#pragma unroll
    for (int kf = 0; kf < 4; ++kf) qf[kf] = *(const bf16x8*)(Qp + kf * 32);

    f32x4 o[8];
    f32x4 vzero = {0.f, 0.f, 0.f, 0.f};
#pragma unroll
    for (int i = 0; i < 8; ++i) o[i] = vzero;
    float m_run = NEGF, l_run = 0.f;     // per-lane: q-row = q0 + lr

    const float* biasp = bias + (((size_t)(b * H_ + h)) << 20)
                              + (((size_t)(q0 + lr)) << 10);
    const unsigned char* mp = maskc + ((size_t)b << 20)
                              + (((size_t)(q0 + lr)) << 10);
    const unsigned short* Kg = KV + (size_t)(b * S_) * KSTR + h * DH_;
    const unsigned short* Vg = Vtw + (((size_t)(b * H_ + h)) * DH_) * S_;

    float4 br0[4], br1[4];
    unsigned int mr0[4], mr1[4];

#define STAGE_KV(KT, BUF)                                                          \
    do { int kv0_ = (KT) << 6;                                                     \
        _Pragma("unroll")                                                          \
        for (int c = 0; c < 4; ++c) {                                              \
            int seg = (w << 2) + c;                                                \
            int krow = (seg << 2) + (l >> 4);                                      \
            int kch = (l & 15) ^ (krow & 7);                                       \
            GLD16(Kg + (size_t)(kv0_ + krow) * KSTR + (kch << 3),                  \
                  &Kbuf[BUF][seg << 9], l);                                        \
            int vrow = (seg << 3) + (l >> 3);                                      \
            int vch = (l & 7) ^ (vrow & 7);                                        \
            GLD16(Vg + (size_t)vrow * S_ + kv0_ + (vch << 3),                      \
                  &Vbuf[BUF][seg << 9], l);                                        \
        }                                                                          \
    } while (0)

#define LOAD_BM(BR, MR, KT)                                                        \
    do { int kv0_ = (KT) << 6;                                                     \
        _Pragma("unroll")                                                          \
        for (int nb = 0; nb < 4; ++nb) {                                           \
            BR[nb] = *(const float4*)(biasp + kv0_ + (nb << 4) + (lg << 2));       \
            MR[nb] = *(const unsigned int*)(mp + kv0_ + (nb << 4) + (lg << 2));    \
        }                                                                          \
    } while (0)

#define COMPUTE(BUF, BR, MR)                                                       \
    do {                                                                           \
        f32x4 s_[4];                                                               \
        __builtin_amdgcn_s_setprio(1);                                             \
        _Pragma("unroll")                                                          \
        for (int nb = 0; nb < 4; ++nb) {                                           \
            s_[nb] = vzero;                                                        \
            int krow = (nb << 4) + lr;                                             \
            _Pragma("unroll")                                                      \
            for (int kf = 0; kf < 4; ++kf) {                                       \
                int ba = ((krow << 8) + (((kf << 5) + (lg << 3)) << 1))            \
                         ^ ((krow & 7) << 4);                                      \
                bf16x8 kfr = *(const bf16x8*)((const char*)Kbuf[BUF] + ba);        \
                s_[nb] = mfma16(kfr, qf[kf], s_[nb]);                              \
            }                                                                      \
        }                                                                          \
        __builtin_amdgcn_s_setprio(0);                                             \
        float sv[4][4];                                                            \
        _Pragma("unroll")                                                          \
        for (int nb = 0; nb < 4; ++nb) {                                           \
            float bb[4] = {BR[nb].x, BR[nb].y, BR[nb].z, BR[nb].w};                \
            _Pragma("unroll")                                                      \
            for (int r = 0; r < 4; ++r) {                                          \
                float x2 = fmaf(s_[nb][r], 0.08838834764831845f, bb[r]);           \
                sv[nb][r] = ((MR[nb] >> (r * 8)) & 0xffu) ? x2 : NEGF;             \
            }                                                                      \
        }                                                                          \
        float mt = sv[0][0];                                                       \
        _Pragma("unroll")                                                          \
        for (int nb = 0; nb < 4; ++nb)                                             \
            _Pragma("unroll")                                                      \
            for (int r = 0; r < 4; ++r) mt = fmaxf(mt, sv[nb][r]);                 \
        mt = fmaxf(mt, __shfl_xor(mt, 16, 64));                                    \
        mt = fmaxf(mt, __shfl_xor(mt, 32, 64));                                    \
        float mn = fmaxf(m_run, mt);                                               \
        float al = __expf(m_run - mn);                                             \
        m_run = mn;                                                                \
        float rs = 0.f;                                                            \
        _Pragma("unroll")                                                          \
        for (int nb = 0; nb < 4; ++nb)                                             \
            _Pragma("unroll")                                                      \
            for (int r = 0; r < 4; ++r) {                                          \
                sv[nb][r] = __expf(sv[nb][r] - m_run);                             \
                rs += sv[nb][r];                                                   \
            }                                                                      \
        rs += __shfl_xor(rs, 16, 64);                                              \
        rs += __shfl_xor(rs, 32, 64);                                              \
        l_run = l_run * al + rs;                                                   \
        float alm[4];                                                              \
        _Pragma("unroll")                                                          \
        for (int r = 0; r < 4; ++r) alm[r] = __shfl(al, (lg << 2) + r, 64);        \
        _Pragma("unroll")                                                          \
        for (int nb2 = 0; nb2 < 8; ++nb2) {                                        \
            o[nb2][0] *= alm[0]; o[nb2][1] *= alm[1];                              \
            o[nb2][2] *= alm[2]; o[nb2][3] *= alm[3];                              \
        }                                                                          \
        _Pragma("unroll")                                                          \
        for (int nb = 0; nb < 4; ++nb)                                             \
            _Pragma("unroll")                                                      \
            for (int r = 0; r < 4; ++r)                                            \
                Plds[w][lr * 72 + (nb << 4) + (lg << 2) + r] = f32_to_bf16(sv[nb][r]); \
        __builtin_amdgcn_s_setprio(1);                                             \
        _Pragma("unroll")                                                          \
        for (int kf2 = 0; kf2 < 2; ++kf2) {                                        \
            bf16x8 pf = *(const bf16x8*)&Plds[w][lr * 72 + (kf2 << 5) + (lg << 3)]; \
            _Pragma("unroll")                                                      \
            for (int nb2 = 0; nb2 < 8; ++nb2) {                                    \
                int dh = (nb2 << 4) + lr;                                          \
                int ba = ((dh << 7) + (((kf2 << 5) + (lg << 3)) << 1))             \
                         ^ ((dh & 7) << 4);                                        \
                bf16x8 vf = *(const bf16x8*)((const char*)Vbuf[BUF] + ba);         \
                o[nb2] = mfma16(pf, vf, o[nb2]);                                   \
            }                                                                      \
        }                                                                          \
        __builtin_amdgcn_s_setprio(0);                                             \
    } while (0)

    STAGE_KV(0, 0);
    LOAD_BM(br0, mr0, 0);

#pragma unroll 1
    for (int kt = 0; kt < 16; kt += 2) {
        __syncthreads();
        STAGE_KV(kt + 1, 1);
        LOAD_BM(br1, mr1, kt + 1);
        COMPUTE(0, br0, mr0);
        __syncthreads();
        if (kt < 14) {
            STAGE_KV(kt + 2, 0);
            LOAD_BM(br0, mr0, kt + 2);
        }
        COMPUTE(1, br1, mr1);
    }

    float lm[4];
#pragma unroll
    for (int r = 0; r < 4; ++r) lm[r] = __shfl(l_run, (lg << 2) + r, 64);
#pragma unroll
    for (int r = 0; r < 4; ++r) {
        float inv = lm[r] > 0.f ? 1.0f / lm[r] : 0.f;
        int q = q0 + (lg << 2) + r;
        unsigned short* cp = ctx + ((size_t)(b * S_ + q)) * D_ + h * DH_ + lr;
#pragma unroll
        for (int nb2 = 0; nb2 < 8; ++nb2)
            cp[nb2 * 16] = f32_to_bf16(o[nb2][r] * inv);
    }
#undef STAGE_KV
#undef LOAD_BM
#undef COMPUTE
}

// ---------------------------------------------------------------------------
extern "C" void kernel_launch(void* const* d_in, const int* in_sizes, int n_in,
                              void* d_out, int out_size, void* d_ws, size_t ws_size,
                              hipStream_t stream) {
    const float* hq   = (const float*)d_in[0];
    const float* hkv  = (const float*)d_in[1];
    const void*  mask = d_in[2];
    const float* bias = (const float*)d_in[3];
    const float* Wq   = (const float*)d_in[4];
    const float* Wk   = (const float*)d_in[5];
    const float* Wv   = (const float*)d_in[6];
    const float* Wo   = (const float*)d_in[7];
    float* out = (float*)d_out;

    char* ws = (char*)d_ws;
    unsigned char* mask_c = (unsigned char*)ws;                        // 2 MB
    unsigned short* hq_b  = (unsigned short*)(ws + (2u << 20) + 4096); // 16 MB
    unsigned short* hkv_b = hq_b + ((size_t)1 << 23);                  // 16 MB
    unsigned short* WTq   = hkv_b + ((size_t)1 << 23);                 // 32 MB
    unsigned short* WTo   = WTq + ((size_t)1 << 24);                   // 32 MB
    unsigned short* WTkv  = WTo + ((size_t)1 << 24);                   // 64 MB
    unsigned short* Qws   = WTkv + ((size_t)1 << 25);                  // 16 MB
    unsigned short* KVws  = Qws + ((size_t)1 << 23);                   // 32 MB
    unsigned short* Cws   = KVws + ((size_t)1 << 24);                  // 16 MB
    unsigned short* Vtw   = Cws + ((size_t)1 << 23);                   // 16 MB
    float* Pws            = (float*)(Vtw + ((size_t)1 << 23));         // 64 MB

    prep_kernel<<<40960, 256, 0, stream>>>(Wq, Wk, Wv, Wo, WTq, WTkv, WTo,
                                           mask, mask_c, hq, hkv, hq_b, hkv_b);

    gemm_qkv_kernel<<<512, 512, 0, stream>>>(hq_b, WTq, Pws, hkv_b, WTkv, KVws);
    vtrq_kernel<<<10240, 256, 0, stream>>>(KVws, Vtw, Pws, Qws);

    attn_kernel<<<B_ * H_ * (S_ / 64), 256, 0, stream>>>(Qws, KVws, Vtw, bias, mask_c, Cws);

    gemm_o_kernel<<<256, 512, 0, stream>>>(Cws, WTo, Pws);
    reduce_o_kernel<<<(M_ * D_) / 1024, 256, 0, stream>>>(Pws, out);
}

// Round 17
// 480.862 us; speedup vs baseline: 1.2286x; 1.0161x over previous
//
#include <hip/hip_runtime.h>
#include <stdint.h>

// ---------------------------------------------------------------------------
// CPMAntAttention: B=2,S=1024,D=4096,H=32,DH=128
// Round 17: fold reduce_q into attn's Q-load (attn reads the two fp32 Q
// partial buffers directly, adds + converts in-register; numerically
// identical). vtrq shrinks to pure V-transpose (2048 blocks). Saves the
// 16MB bf16 Q intermediate write+read + dispatch width. Everything else
// identical to r16 best (prep fusion, 10-slot GEMM core, r13 attn loop).
// ---------------------------------------------------------------------------

#define B_  2
#define S_  1024
#define D_  4096
#define H_  32
#define DH_ 128
#define M_  (B_ * S_)          // 2048
#define KSTR 8192              // row stride of fused KV output

typedef __attribute__((ext_vector_type(8))) short bf16x8;
typedef __attribute__((ext_vector_type(8))) unsigned short u16x8;
typedef __attribute__((ext_vector_type(4))) float f32x4;

static __device__ __forceinline__ unsigned short f32_to_bf16(float f) {
    unsigned int x = __float_as_uint(f);
    x += 0x7fffu + ((x >> 16) & 1u);   // RNE
    return (unsigned short)(x >> 16);
}

static __device__ __forceinline__ f32x4 mfma16(bf16x8 a, bf16x8 b, f32x4 c) {
    return __builtin_amdgcn_mfma_f32_16x16x32_bf16(a, b, c, 0, 0, 0);
}

#if defined(__has_builtin)
#if __has_builtin(__builtin_amdgcn_global_load_lds)
#define HAVE_GLOAD_LDS 1
#endif
#endif

#ifdef HAVE_GLOAD_LDS
#define GLD16(g, lbase, lane)                                                  \
    __builtin_amdgcn_global_load_lds(                                          \
        (const __attribute__((address_space(1))) void*)(g),                    \
        (__attribute__((address_space(3))) void*)(lbase), 16, 0, 0)
#else
#define GLD16(g, lbase, lane)                                                  \
    do { *(bf16x8*)((unsigned short*)(lbase) + (size_t)(lane) * 8) =           \
             *(const bf16x8*)(g); } while (0)
#endif

// ---------------------------------------------------------------------------
// Fused prep: blocks 0..16383 transpose_all | 16384..24575 canon_mask |
// 24576..40959 cvt2. All branches independent (distinct in->out).
__global__ __launch_bounds__(256) void prep_kernel(
        const float* __restrict__ Wq, const float* __restrict__ Wk,
        const float* __restrict__ Wv, const float* __restrict__ Wo,
        unsigned short* __restrict__ WTq, unsigned short* __restrict__ WTkv,
        unsigned short* __restrict__ WTo,
        const void* __restrict__ mask, unsigned char* __restrict__ mask_c,
        const float* __restrict__ hq, const float* __restrict__ hkv,
        unsigned short* __restrict__ hq_b, unsigned short* __restrict__ hkv_b) {
    __shared__ unsigned short lds[64][65];
    __shared__ int sflag;
    int gbid = blockIdx.x;
    int t = threadIdx.x;

    if (gbid < 16384) {
        int which = gbid >> 12;
        int bid = gbid & 4095;
        const float* W = (which == 0) ? Wq : (which == 1) ? Wk : (which == 2) ? Wv : Wo;
        unsigned short* WT = (which == 0) ? WTq
                           : (which == 1) ? WTkv
                           : (which == 2) ? (WTkv + (size_t)4096 * 4096)
                                          : WTo;
        int bx = bid & 63;
        int by = bid >> 6;
        int tr = t >> 4;
        int tc = (t & 15) * 4;
#pragma unroll
        for (int p = 0; p < 4; ++p) {
            int r = p * 16 + tr;
            float4 v = *(const float4*)(W + (size_t)(by * 64 + r) * D_ + bx * 64 + tc);
            lds[r][tc + 0] = f32_to_bf16(v.x);
            lds[r][tc + 1] = f32_to_bf16(v.y);
            lds[r][tc + 2] = f32_to_bf16(v.z);
            lds[r][tc + 3] = f32_to_bf16(v.w);
        }
        __syncthreads();
        int wn = t >> 3;
        int k0 = (t & 7) * 8;
#pragma unroll
        for (int p2 = 0; p2 < 2; ++p2) {
            int n = p2 * 32 + wn;
            u16x8 o;
#pragma unroll
            for (int j = 0; j < 8; ++j) o[j] = lds[k0 + j][n];
            *(u16x8*)(WT + (size_t)(bx * 64 + n) * D_ + by * 64 + k0) = o;
        }
    } else if (gbid < 24576) {
        if (t < 64) {
            uint4 v = ((const uint4*)mask)[t];
            unsigned int ww[4] = {v.x, v.y, v.z, v.w};
            int nz_hi = 0, nz_lo01 = 0;
#pragma unroll
            for (int wi = 0; wi < 4; ++wi)
#pragma unroll
                for (int bi = 0; bi < 4; ++bi) {
                    unsigned int byte = (ww[wi] >> (bi * 8)) & 0xffu;
                    if (byte && bi != 0) nz_hi = 1;
                    if (byte && bi <= 1) nz_lo01 = 1;
                }
            int any_hi = __any(nz_hi);
            int any_lo01 = __any(nz_lo01);
            if (t == 0) sflag = (!any_hi) ? 1 : ((!any_lo01) ? 2 : 0);
        }
        __syncthreads();
        int f = sflag;
        int i = (gbid - 16384) * 256 + t;
        unsigned char v;
        if (f == 1)      v = (unsigned char)(((const int*)mask)[i] != 0);
        else if (f == 2) v = (unsigned char)(((const float*)mask)[i] != 0.0f);
        else             v = (unsigned char)(((const unsigned char*)mask)[i] != 0);
        mask_c[i] = v;
    } else {
        int i = (gbid - 24576) * 256 + t;
        const int n4 = (B_ * S_ * D_) / 4;
        const float* src = (i < n4) ? hq : hkv;
        unsigned short* dst = (i < n4) ? hq_b : hkv_b;
        int j = (i < n4) ? i : i - n4;
        float4 v = ((const float4*)src)[j];
        ushort4 o;
        o.x = f32_to_bf16(v.x); o.y = f32_to_bf16(v.y);
        o.z = f32_to_bf16(v.z); o.w = f32_to_bf16(v.w);
        ((ushort4*)dst)[j] = o;
    }
}

// V-transpose only (reduce_q now fused into attn's Q load). 2048 blocks.
__global__ __launch_bounds__(256) void vt_kernel(const unsigned short* __restrict__ KV,
                                                 unsigned short* __restrict__ Vtw) {
    __shared__ unsigned short lds[64][72];
    int bid = blockIdx.x;
    int t = threadIdx.x;
    int dt = bid & 1;
    int st = (bid >> 1) & 15;
    int h  = (bid >> 5) & 31;
    int b  = bid >> 10;
    int r = t >> 2;
    int c0 = (t & 3) * 16;
    const unsigned short* src =
        KV + (size_t)(b * S_ + st * 64 + r) * KSTR + 4096 + h * DH_ + dt * 64 + c0;
    bf16x8 v0 = *(const bf16x8*)(src);
    bf16x8 v1 = *(const bf16x8*)(src + 8);
    *(bf16x8*)&lds[r][c0] = v0;
    *(bf16x8*)&lds[r][c0 + 8] = v1;
    __syncthreads();
    unsigned short tmp[16];
#pragma unroll
    for (int i = 0; i < 16; ++i) tmp[i] = lds[c0 + i][r];
    unsigned short* dst =
        Vtw + ((size_t)((b * H_ + h) * DH_ + dt * 64 + r)) * S_ + st * 64 + c0;
    *(bf16x8*)dst = *(bf16x8*)&tmp[0];
    *(bf16x8*)(dst + 8) = *(bf16x8*)&tmp[8];
}

// ---------------------------------------------------------------------------
// Phase-pipelined GEMM core (r13): 10-slot ring (160 KiB), prefetch dist 6,
// vmcnt(4) steady / vmcnt(0) final tile. Tile 256x256, BK=64, 512 thr.
__device__ __forceinline__ void gemm_core(const unsigned short* __restrict__ A,
                                          const unsigned short* __restrict__ BT,
                                          void* __restrict__ C, int out_f32,
                                          int m0, int n0, int cstride,
                                          int koff, int NT, char* ldsc) {
    const int t = threadIdx.x;
    const int w = t >> 6, l = t & 63;
    const int lr = l & 15, lg = l >> 4;
    const int wmh = w >> 2;
    const int walf = w & 3;
    const int wm = wmh << 7;
    const int wn = walf << 6;

    const int ca0 = lg ^ (lr & 7);
    const int aoff0 = lr * 128 + (ca0 << 4);
    const int aoff1 = lr * 128 + ((ca0 ^ 4) << 4);
    const int boff0 = ((walf & 1) * 64 + lr) * 128 + (ca0 << 4);
    const int boff1 = ((walf & 1) * 64 + lr) * 128 + ((ca0 ^ 4) << 4);

    const int srow = t >> 3;
    const int sch = (t & 7) ^ (srow & 7);
    const size_t soff0 = (size_t)srow * 4096 + (size_t)(sch << 3);
    const size_t soff1 = soff0 + (size_t)64 * 4096;
    const int ldso = w << 10;

    f32x4 ac[8][4];
    f32x4 vzero = {0.f, 0.f, 0.f, 0.f};
#pragma unroll
    for (int i = 0; i < 8; ++i)
#pragma unroll
        for (int j = 0; j < 4; ++j) ac[i][j] = vzero;

#define STAGE_ELEM(E, SS)                                                      \
    do {                                                                       \
        int er_ = (E) & 3;                                                     \
        const unsigned short* mb_ = (er_ < 2)                                  \
            ? A + (size_t)(m0 + ((er_ & 1) << 7)) * 4096                       \
            : BT + (size_t)(n0 + ((er_ & 1) << 7)) * 4096;                     \
        mb_ += (size_t)((((E) >> 2) << 6) + koff);                             \
        char* d0_ = ldsc + (SS) * 16384 + ldso;                                \
        GLD16(mb_ + soff0, d0_, l);                                            \
        GLD16(mb_ + soff1, d0_ + 8192, l);                                     \
    } while (0)

#pragma unroll
    for (int e = 0; e < 6; ++e) STAGE_ELEM(e, e);

    const int NT4 = NT << 2;
    int E = 6, ss = 6, s0 = 0;
    bf16x8 bfr[4][2];

#pragma unroll 1
    for (int tau = 0; tau < NT; ++tau) {
        int sA = s0 + wmh;             if (sA >= 10) sA -= 10;
        int sB = s0 + 2 + (walf >> 1); if (sB >= 10) sB -= 10;
        const char* pA0 = ldsc + sA * 16384 + aoff0;
        const char* pA1 = ldsc + sA * 16384 + aoff1;
        const char* pB0 = ldsc + sB * 16384 + boff0;
        const char* pB1 = ldsc + sB * 16384 + boff1;
#pragma unroll
        for (int r = 0; r < 4; ++r) {
            if (r == 0) {
                if (tau == NT - 1)
                    asm volatile("s_waitcnt vmcnt(0)" ::: "memory");
                else
                    asm volatile("s_waitcnt vmcnt(4)" ::: "memory");
            }
            __builtin_amdgcn_s_barrier();
            asm volatile("" ::: "memory");
            if (r == 0) {
#pragma unroll
                for (int nf = 0; nf < 4; ++nf) {
                    bfr[nf][0] = *(const bf16x8*)(pB0 + nf * 2048);
                    bfr[nf][1] = *(const bf16x8*)(pB1 + nf * 2048);
                }
            }
            bf16x8 af[2][2];
            int mfb = r << 1;
#pragma unroll
            for (int j = 0; j < 2; ++j) {
                af[j][0] = *(const bf16x8*)(pA0 + (mfb + j) * 2048);
                af[j][1] = *(const bf16x8*)(pA1 + (mfb + j) * 2048);
            }
            if (E < NT4) STAGE_ELEM(E, ss);
            ++E; ss = (ss == 9) ? 0 : ss + 1;
            __builtin_amdgcn_s_setprio(1);
#pragma unroll
            for (int j = 0; j < 2; ++j)
#pragma unroll
                for (int nf = 0; nf < 4; ++nf) {
                    ac[mfb + j][nf] = mfma16(af[j][0], bfr[nf][0], ac[mfb + j][nf]);
                    ac[mfb + j][nf] = mfma16(af[j][1], bfr[nf][1], ac[mfb + j][nf]);
                }
            __builtin_amdgcn_s_setprio(0);
        }
        s0 += 4; if (s0 >= 10) s0 -= 10;
    }
#undef STAGE_ELEM

#pragma unroll
    for (int mf = 0; mf < 8; ++mf)
#pragma unroll
        for (int nf = 0; nf < 4; ++nf)
#pragma unroll
            for (int q = 0; q < 4; ++q) {
                int row = m0 + wm + mf * 16 + lg * 4 + q;
                int col = n0 + wn + nf * 16 + lr;
                if (out_f32)
                    ((float*)C)[(size_t)row * cstride + col] = ac[mf][nf][q];
                else
                    ((unsigned short*)C)[(size_t)row * cstride + col] = f32_to_bf16(ac[mf][nf][q]);
            }
}

// 512 blocks, two homogeneous rounds: 0..255 KV full-K, 256..511 Q splitK2.
__global__ __launch_bounds__(512, 1) void gemm_qkv_kernel(
        const unsigned short* __restrict__ Aq, const unsigned short* __restrict__ Bq,
        float* __restrict__ Pq,
        const unsigned short* __restrict__ Akv, const unsigned short* __restrict__ Bkv,
        unsigned short* __restrict__ Ckv) {
    __shared__ char ldsbuf[10 * 16384];
    int bid = blockIdx.x;
    if (bid < 256) {
        int bm = bid & 7, bn = bid >> 3;
        gemm_core(Akv, Bkv, Ckv, 0, bm << 8, bn << 8, 8192, 0, 64, ldsbuf);
    } else {
        int e = bid - 256;
        int bm = e & 7;
        int rest = e >> 3;
        int bn = rest & 15;
        int ks = rest >> 4;
        gemm_core(Aq, Bq, Pq + (size_t)ks * M_ * D_, 1, bm << 8, bn << 8, 4096,
                  ks * 2048, 32, ldsbuf);
    }
}

__global__ __launch_bounds__(512, 1) void gemm_o_kernel(
        const unsigned short* __restrict__ A, const unsigned short* __restrict__ BT,
        float* __restrict__ P) {
    __shared__ char ldsbuf[10 * 16384];
    int bid = blockIdx.x;
    int bm = bid & 7;
    int rest = bid >> 3;
    int bn = rest & 15;
    int ks = rest >> 4;
    gemm_core(A, BT, P + (size_t)ks * M_ * D_, 1, bm << 8, bn << 8, 4096,
              ks * 2048, 32, ldsbuf);
}

__global__ void reduce_o_kernel(const float* __restrict__ P, float* __restrict__ out) {
    int i = blockIdx.x * 256 + threadIdx.x;
    float4 a = ((const float4*)P)[i];
    float4 b = ((const float4*)(P + (size_t)M_ * D_))[i];
    float4 o; o.x = a.x + b.x; o.y = a.y + b.y; o.z = a.z + b.z; o.w = a.w + b.w;
    ((float4*)out)[i] = o;
}

// ---------------------------------------------------------------------------
// Flash attention (r13 loop, proven local optimum) with fused Q-reduce:
// Q fragments assembled from the two fp32 split-K partial buffers (add +
// RNE->bf16 in-register; identical numerics to reduce_q + bf16 load).
#define NEGF (-1e30f)
__global__ __launch_bounds__(256, 2) void attn_kernel(const float* __restrict__ Pq,
                                                      const unsigned short* __restrict__ KV,
                                                      const unsigned short* __restrict__ Vtw,
                                                      const float* __restrict__ bias,
                                                      const unsigned char* __restrict__ maskc,
                                                      unsigned short* __restrict__ ctx) {
    __shared__ unsigned short Kbuf[2][64 * 128];
    __shared__ unsigned short Vbuf[2][128 * 64];
    __shared__ unsigned short Plds[4][16 * 72];

    int x = blockIdx.x;
    int xcd = x & 7;
    int rest = x >> 3;           // 0..127
    int qt = rest & 15;
    int gq = rest >> 4;          // 0..7
    int g = gq * 8 + xcd;        // 0..63
    int b = g >> 5, h = g & 31;

    int t = threadIdx.x, w = t >> 6, l = t & 63;
    int lr = l & 15, lg = l >> 4;
    int q0 = (qt << 6) + (w << 4);

    // Q fragments from fp32 partials: row q0+lr, cols h*DH + lg*8 + kf*32 ..+7
    bf16x8 qf[4];
    {
        const float* p0 = Pq + ((size_t)(b * S_ + q0 + lr)) * D_ + h * DH_ + lg * 8;
        const float* p1 = p0 + (size_t)M_ * D_;
#pragma unroll
        for (int kf = 0; kf < 4; ++kf) {
            float4 a0 = *(const float4*)(p0 + kf * 32);
            float4 a1 = *(const float4*)(p0 + kf * 32 + 4);
            float4 b0 = *(const float4*)(p1 + kf * 32);
            float4 b1 = *(const float4*)(p1 + kf * 32 + 4);
            qf[kf][0] = (short)f32_to_bf16(a0.x + b0.x);
            qf[kf][1] = (short)f32_to_bf16(a0.y + b0.y);
            qf[kf][2] = (short)f32_to_bf16(a0.z + b0.z);
            qf[kf][3] = (short)f32_to_bf16(a0.w + b0.w);
            qf[kf][4] = (short)f32_to_bf16(a1.x + b1.x);
            qf[kf][5] = (short)f32_to_bf16(a1.y + b1.y);
            qf[kf][6] = (short)f32_to_bf16(a1.z + b1.z);
            qf[kf][7] = (short)f32_to_bf16(a1.w + b1.w);
        }
    }

    f32x4 o[8];
    f32x4 vzero = {0.f, 0.f, 0.f, 0.f};
#pragma unroll
    for (int i = 0; i < 8; ++i) o[i] = vzero;
    float m_run = NEGF, l_run = 0.f;     // per-lane: q-row = q0 + lr

    const float* biasp = bias + (((size_t)(b * H_ + h)) << 20)
                              + (((size_t)(q0 + lr)) << 10);
    const unsigned char* mp = maskc + ((size_t)b << 20)
                              + (((size_t)(q0 + lr)) << 10);
    const unsigned short* Kg = KV + (size_t)(b * S_) * KSTR + h * DH_;
    const unsigned short* Vg = Vtw + (((size_t)(b * H_ + h)) * DH_) * S_;

    float4 br0[4], br1[4];
    unsigned int mr0[4], mr1[4];

#define STAGE_KV(KT, BUF)                                                          \
    do { int kv0_ = (KT) << 6;                                                     \
        _Pragma("unroll")                                                          \
        for (int c = 0; c < 4; ++c) {                                              \
            int seg = (w << 2) + c;                                                \
            int krow = (seg << 2) + (l >> 4);                                      \
            int kch = (l & 15) ^ (krow & 7);                                       \
            GLD16(Kg + (size_t)(kv0_ + krow) * KSTR + (kch << 3),                  \
                  &Kbuf[BUF][seg << 9], l);                                        \
            int vrow = (seg << 3) + (l >> 3);                                      \
            int vch = (l & 7) ^ (vrow & 7);                                        \
            GLD16(Vg + (size_t)vrow * S_ + kv0_ + (vch << 3),                      \
                  &Vbuf[BUF][seg << 9], l);                                        \
        }                                                                          \
    } while (0)

#define LOAD_BM(BR, MR, KT)                                                        \
    do { int kv0_ = (KT) << 6;                                                     \
        _Pragma("unroll")                                                          \
        for (int nb = 0; nb < 4; ++nb) {                                           \
            BR[nb] = *(const float4*)(biasp + kv0_ + (nb << 4) + (lg << 2));       \
            MR[nb] = *(const unsigned int*)(mp + kv0_ + (nb << 4) + (lg << 2));    \
        }                                                                          \
    } while (0)

#define COMPUTE(BUF, BR, MR)                                                       \
    do {                                                                           \
        f32x4 s_[4];                                                               \
        __builtin_amdgcn_s_setprio(1);                                             \
        _Pragma("unroll")                                                          \
        for (int nb = 0; nb < 4; ++nb) {                                           \
            s_[nb] = vzero;                                                        \
            int krow = (nb << 4) + lr;                                             \
            _Pragma("unroll")                                                      \
            for (int kf = 0; kf < 4; ++kf) {                                       \
                int ba = ((krow << 8) + (((kf << 5) + (lg << 3)) << 1))            \
                         ^ ((krow & 7) << 4);                                      \
                bf16x8 kfr = *(const bf16x8*)((const char*)Kbuf[BUF] + ba);        \
                s_[nb] = mfma16(kfr, qf[kf], s_[nb]);                              \
            }                                                                      \
        }                                                                          \
        __builtin_amdgcn_s_setprio(0);                                             \
        float sv[4][4];                                                            \
        _Pragma("unroll")                                                          \
        for (int nb = 0; nb < 4; ++nb) {                                           \
            float bb[4] = {BR[nb].x, BR[nb].y, BR[nb].z, BR[nb].w};                \
            _Pragma("unroll")                                                      \
            for (int r = 0; r < 4; ++r) {                                          \
                float x2 = fmaf(s_[nb][r], 0.08838834764831845f, bb[r]);           \
                sv[nb][r] = ((MR[nb] >> (r * 8)) & 0xffu) ? x2 : NEGF;             \
            }                                                                      \
        }                                                                          \
        float mt = sv[0][0];                                                       \
        _Pragma("unroll")                                                          \
        for (int nb = 0; nb < 4; ++nb)                                             \
            _Pragma("unroll")                                                      \
            for (int r = 0; r < 4; ++r) mt = fmaxf(mt, sv[nb][r]);                 \
        mt = fmaxf(mt, __shfl_xor(mt, 16, 64));                                    \
        mt = fmaxf(mt, __shfl_xor(mt, 32, 64));                                    \
        float mn = fmaxf(m_run, mt);                                               \
        float al = __expf(m_run - mn);                                             \
        m_run = mn;                                                                \
        float rs = 0.f;                                                            \
        _Pragma("unroll")                                                          \
        for (int nb = 0; nb < 4; ++nb)                                             \
            _Pragma("unroll")                                                      \
            for (int r = 0; r < 4; ++r) {                                          \
                sv[nb][r] = __expf(sv[nb][r] - m_run);                             \
                rs += sv[nb][r];                                                   \
            }                                                                      \
        rs += __shfl_xor(rs, 16, 64);                                              \
        rs += __shfl_xor(rs, 32, 64);                                              \
        l_run = l_run * al + rs;                                                   \
        float alm[4];                                                              \
        _Pragma("unroll")                                                          \
        for (int r = 0; r < 4; ++r) alm[r] = __shfl(al, (lg << 2) + r, 64);        \
        _Pragma("unroll")                                                          \
        for (int nb2 = 0; nb2 < 8; ++nb2) {                                        \
            o[nb2][0] *= alm[0]; o[nb2][1] *= alm[1];                              \
            o[nb2][2] *= alm[2]; o[nb2][3] *= alm[3];                              \
        }                                                                          \
        _Pragma("unroll")                                                          \
        for (int nb = 0; nb < 4; ++nb)                                             \
            _Pragma("unroll")                                                      \
            for (int r = 0; r < 4; ++r)                                            \
                Plds[w][lr * 72 + (nb << 4) + (lg << 2) + r] = f32_to_bf16(sv[nb][r]); \
        __builtin_amdgcn_s_setprio(1);                                             \
        _Pragma("unroll")                                                          \
        for (int kf2 = 0; kf2 < 2; ++kf2) {                                        \
            bf16x8 pf = *(const bf16x8*)&Plds[w][lr * 72 + (kf2 << 5) + (lg << 3)]; \
            _Pragma("unroll")                                                      \
            for (int nb2 = 0; nb2 < 8; ++nb2) {                                    \
                int dh = (nb2 << 4) + lr;                                          \
                int ba = ((dh << 7) + (((kf2 << 5) + (lg << 3)) << 1))             \
                         ^ ((dh & 7) << 4);                                        \
                bf16x8 vf = *(const bf16x8*)((const char*)Vbuf[BUF] + ba);         \
                o[nb2] = mfma16(pf, vf, o[nb2]);                                   \
            }                                                                      \
        }                                                                          \
        __builtin_amdgcn_s_setprio(0);                                             \
    } while (0)

    STAGE_KV(0, 0);
    LOAD_BM(br0, mr0, 0);

#pragma unroll 1
    for (int kt = 0; kt < 16; kt += 2) {
        __syncthreads();
        STAGE_KV(kt + 1, 1);
        LOAD_BM(br1, mr1, kt + 1);
        COMPUTE(0, br0, mr0);
        __syncthreads();
        if (kt < 14) {
            STAGE_KV(kt + 2, 0);
            LOAD_BM(br0, mr0, kt + 2);
        }
        COMPUTE(1, br1, mr1);
    }

    float lm[4];
#pragma unroll
    for (int r = 0; r < 4; ++r) lm[r] = __shfl(l_run, (lg << 2) + r, 64);
#pragma unroll
    for (int r = 0; r < 4; ++r) {
        float inv = lm[r] > 0.f ? 1.0f / lm[r] : 0.f;
        int q = q0 + (lg << 2) + r;
        unsigned short* cp = ctx + ((size_t)(b * S_ + q)) * D_ + h * DH_ + lr;
#pragma unroll
        for (int nb2 = 0; nb2 < 8; ++nb2)
            cp[nb2 * 16] = f32_to_bf16(o[nb2][r] * inv);
    }
#undef STAGE_KV
#undef LOAD_BM
#undef COMPUTE
}

// ---------------------------------------------------------------------------
extern "C" void kernel_launch(void* const* d_in, const int* in_sizes, int n_in,
                              void* d_out, int out_size, void* d_ws, size_t ws_size,
                              hipStream_t stream) {
    const float* hq   = (const float*)d_in[0];
    const float* hkv  = (const float*)d_in[1];
    const void*  mask = d_in[2];
    const float* bias = (const float*)d_in[3];
    const float* Wq   = (const float*)d_in[4];
    const float* Wk   = (const float*)d_in[5];
    const float* Wv   = (const float*)d_in[6];
    const float* Wo   = (const float*)d_in[7];
    float* out = (float*)d_out;

    char* ws = (char*)d_ws;
    unsigned char* mask_c = (unsigned char*)ws;                        // 2 MB
    unsigned short* hq_b  = (unsigned short*)(ws + (2u << 20) + 4096); // 16 MB
    unsigned short* hkv_b = hq_b + ((size_t)1 << 23);                  // 16 MB
    unsigned short* WTq   = hkv_b + ((size_t)1 << 23);                 // 32 MB
    unsigned short* WTo   = WTq + ((size_t)1 << 24);                   // 32 MB
    unsigned short* WTkv  = WTo + ((size_t)1 << 24);                   // 64 MB
    unsigned short* Qws   = WTkv + ((size_t)1 << 25);                  // 16 MB (unused now)
    unsigned short* KVws  = Qws + ((size_t)1 << 23);                   // 32 MB
    unsigned short* Cws   = KVws + ((size_t)1 << 24);                  // 16 MB
    unsigned short* Vtw   = Cws + ((size_t)1 << 23);                   // 16 MB
    float* Pws            = (float*)(Vtw + ((size_t)1 << 23));         // 64 MB (Q partials, then O partials)

    prep_kernel<<<40960, 256, 0, stream>>>(Wq, Wk, Wv, Wo, WTq, WTkv, WTo,
                                           mask, mask_c, hq, hkv, hq_b, hkv_b);

    gemm_qkv_kernel<<<512, 512, 0, stream>>>(hq_b, WTq, Pws, hkv_b, WTkv, KVws);
    vt_kernel<<<2048, 256, 0, stream>>>(KVws, Vtw);

    attn_kernel<<<B_ * H_ * (S_ / 64), 256, 0, stream>>>(Pws, KVws, Vtw, bias, mask_c, Cws);

    gemm_o_kernel<<<256, 512, 0, stream>>>(Cws, WTo, Pws);
    reduce_o_kernel<<<(M_ * D_) / 1024, 256, 0, stream>>>(Pws, out);
}